// Round 1
// baseline (320.756 us; speedup 1.0000x reference)
//
#include <hip/hip_runtime.h>
#include <hip/hip_bf16.h>
#include <stdint.h>

// Problem dims
#define NB 8
#define NSQ 1024
#define NSK 1024
#define ND 1024
#define NH 16
#define NDH 64
#define NM (NB * NSQ)   // 8192 rows

typedef __bf16 bf16;
typedef __bf16 bf16x8 __attribute__((ext_vector_type(8)));
typedef float f32x4 __attribute__((ext_vector_type(4)));

// ---------------- async global->LDS (16B per lane) ----------------
__device__ __forceinline__ void async_load16(const void* g, void* l) {
  __builtin_amdgcn_global_load_lds(
      (__attribute__((address_space(1))) void*)g,
      (__attribute__((address_space(3))) void*)l, 16, 0, 0);
}

// ---------------- f32 -> bf16 converter (Q, K) ----------------
__global__ __launch_bounds__(256) void cvt_f32_bf16(const float* __restrict__ in,
                                                    bf16* __restrict__ out, int n4) {
  int i = blockIdx.x * 256 + threadIdx.x;
  if (i < n4) {
    float4 v = *(const float4*)(in + (size_t)i * 4);
    union { uint64_t u; bf16 h[4]; } o;
    o.h[0] = (bf16)v.x; o.h[1] = (bf16)v.y; o.h[2] = (bf16)v.z; o.h[3] = (bf16)v.w;
    *(uint64_t*)(out + (size_t)i * 4) = o.u;
  }
}

// ---------------- W [K,N] f32 -> Wt [N,K] bf16 (tiled transpose) ----------------
__global__ __launch_bounds__(256) void transpose_cvt(const float* __restrict__ W,
                                                     bf16* __restrict__ Wt) {
  __shared__ float t[64][65];
  const int bc = blockIdx.x * 64;  // col tile in W (= row tile in Wt)
  const int br = blockIdx.y * 64;  // row tile in W
  const int tid = threadIdx.x;
  for (int c = tid; c < 1024; c += 256) {      // 64 rows x 16 float4 chunks
    int r = c >> 4, off = (c & 15) * 4;
    float4 v = *(const float4*)&W[(size_t)(br + r) * 1024 + bc + off];
    t[r][off] = v.x; t[r][off + 1] = v.y; t[r][off + 2] = v.z; t[r][off + 3] = v.w;
  }
  __syncthreads();
  for (int c = tid; c < 512; c += 256) {       // 64 out-rows x 8 chunks of 8 bf16
    int cc = c >> 3, rr = (c & 7) * 8;
    union { uint4 u; bf16 h[8]; } o;
#pragma unroll
    for (int i = 0; i < 8; ++i) o.h[i] = (bf16)t[rr + i][cc];
    *(uint4*)&Wt[(size_t)(bc + cc) * 1024 + br + rr] = o.u;
  }
}

// ---------------- v [B,SK,D] bf16 -> vT [B,H,DH,SK] bf16 ----------------
__global__ __launch_bounds__(256) void transpose_v(const bf16* __restrict__ vb,
                                                   bf16* __restrict__ vT) {
  // grid: (SK/64, B*H)
  const int st = blockIdx.x * 64;
  const int bh = blockIdx.y;
  const int b = bh >> 4, h = bh & 15;
  __shared__ __align__(16) bf16 t[64][72];
  const int tid = threadIdx.x;
  for (int c = tid; c < 512; c += 256) {   // 64 s-rows x 8 chunks of 8 (d)
    int s = c >> 3, off = (c & 7) * 8;
    *(uint4*)&t[s][off] =
        *(const uint4*)&vb[((size_t)(b * NSK + st + s)) * ND + h * NDH + off];
  }
  __syncthreads();
  for (int c = tid; c < 512; c += 256) {   // 64 d-rows x 8 chunks of 8 (s)
    int d = c >> 3, s0 = (c & 7) * 8;
    union { uint4 u; bf16 h[8]; } o;
#pragma unroll
    for (int i = 0; i < 8; ++i) o.h[i] = t[s0 + i][d];
    *(uint4*)&vT[((size_t)(bh * NDH + d)) * NSK + st + s0] = o.u;
  }
}

// ---------------- GEMM: C[M,N] = A[M,K] @ Bt[N,K]^T + bias ----------------
// MODE 0: write bf16 C.   MODE 1: write f32 C = Res + relu(acc + bias).
template <int MODE>
__global__ __launch_bounds__(256) void gemm_bt(
    const bf16* __restrict__ A, const bf16* __restrict__ Bt,
    const float* __restrict__ bias, bf16* __restrict__ Cb,
    float* __restrict__ Cf, const float* __restrict__ Res,
    int M, int N, int K) {
  __shared__ __align__(16) bf16 As[128 * 32];
  __shared__ __align__(16) bf16 Bs[128 * 32];
  const int tid = threadIdx.x;
  const int bcol = blockIdx.x * 128;
  const int brow = blockIdx.y * 128;
  const int w = tid >> 6, lane = tid & 63;
  const int wm = w >> 1, wn = w & 1;
  const int lr = lane & 15;
  const int lk = (lane >> 4) * 8;
  const int rgrp = (lane >> 4) * 4;

  f32x4 acc[4][4] = {};

  const int c0 = tid, c1 = tid + 256;  // 16B chunks (8 bf16) per tile of 8KB
  for (int k0 = 0; k0 < K; k0 += 32) {
    __syncthreads();
    async_load16(A + (size_t)(brow + (c0 >> 2)) * K + k0 + (c0 & 3) * 8, &As[c0 * 8]);
    async_load16(A + (size_t)(brow + (c1 >> 2)) * K + k0 + (c1 & 3) * 8, &As[c1 * 8]);
    async_load16(Bt + (size_t)(bcol + (c0 >> 2)) * K + k0 + (c0 & 3) * 8, &Bs[c0 * 8]);
    async_load16(Bt + (size_t)(bcol + (c1 >> 2)) * K + k0 + (c1 & 3) * 8, &Bs[c1 * 8]);
    __syncthreads();
    bf16x8 af[4], bf[4];
#pragma unroll
    for (int m = 0; m < 4; ++m)
      af[m] = *(const bf16x8*)&As[(wm * 64 + m * 16 + lr) * 32 + lk];
#pragma unroll
    for (int n = 0; n < 4; ++n)
      bf[n] = *(const bf16x8*)&Bs[(wn * 64 + n * 16 + lr) * 32 + lk];
#pragma unroll
    for (int m = 0; m < 4; ++m)
#pragma unroll
      for (int n = 0; n < 4; ++n)
        acc[m][n] = __builtin_amdgcn_mfma_f32_16x16x32_bf16(af[m], bf[n], acc[m][n], 0, 0, 0);
  }
#pragma unroll
  for (int m = 0; m < 4; ++m) {
#pragma unroll
    for (int n = 0; n < 4; ++n) {
      const int col = bcol + wn * 64 + n * 16 + lr;
      const float bv = bias[col];
#pragma unroll
      for (int r = 0; r < 4; ++r) {
        const int row = brow + wm * 64 + m * 16 + rgrp + r;
        float v = acc[m][n][r] + bv;
        if (MODE == 0) {
          Cb[(size_t)row * N + col] = (bf16)v;
        } else {
          float res = Res[(size_t)row * N + col];
          Cf[(size_t)row * N + col] = res + (v > 0.f ? v : 0.f);
        }
      }
    }
  }
}

// ---------------- fused attention (per (b,h), 64 q-rows per block) ----------------
__global__ __launch_bounds__(256) void attn_kernel(
    const bf16* __restrict__ qb, const bf16* __restrict__ kb,
    const bf16* __restrict__ vT, float* __restrict__ attnout) {
  // grid: (SQ/64, B*H)
  const int qt = blockIdx.x * 64;
  const int bh = blockIdx.y;
  const int b = bh >> 4, h = bh & 15;
  const int tid = threadIdx.x, w = tid >> 6, lane = tid & 63;
  const int lr = lane & 15;
  const int lk = (lane >> 4) * 8;
  const int rgrp = (lane >> 4) * 4;

  __shared__ __align__(16) bf16 Kt[64 * 72];
  __shared__ __align__(16) bf16 Vt[64 * 72];
  __shared__ __align__(16) bf16 Pl[4][16 * 72];

  const int q0 = qt + w * 16;
  bf16x8 aQ[2];
#pragma unroll
  for (int kd = 0; kd < 2; ++kd)
    aQ[kd] = *(const bf16x8*)&qb[((size_t)(b * NSQ + q0 + lr)) * ND + h * NDH + kd * 32 + lk];

  f32x4 oacc[4] = {};
  float mrow[4], lrow[4];
#pragma unroll
  for (int r = 0; r < 4; ++r) { mrow[r] = -1e30f; lrow[r] = 0.f; }
  const float scale = 0.03125f;  // 1/sqrt(1024)

  for (int kt = 0; kt < NSK; kt += 64) {
    __syncthreads();
    for (int c = tid; c < 512; c += 256) {  // stage K tile + V tile (padded LDS)
      int r = c >> 3, off = (c & 7) * 8;
      *(uint4*)&Kt[r * 72 + off] =
          *(const uint4*)&kb[((size_t)(b * NSK + kt + r)) * ND + h * NDH + off];
      *(uint4*)&Vt[r * 72 + off] =
          *(const uint4*)&vT[((size_t)(bh * NDH + r)) * NSK + kt + off];
    }
    __syncthreads();
    // S = Q K^T for this wave's 16 rows x 64 keys
    f32x4 sfr[4] = {};
#pragma unroll
    for (int n = 0; n < 4; ++n)
#pragma unroll
      for (int kd = 0; kd < 2; ++kd) {
        bf16x8 bk = *(const bf16x8*)&Kt[(n * 16 + lr) * 72 + kd * 32 + lk];
        sfr[n] = __builtin_amdgcn_mfma_f32_16x16x32_bf16(aQ[kd], bk, sfr[n], 0, 0, 0);
      }
    // online softmax
    float p[4][4], mnew[4], psum[4];
#pragma unroll
    for (int r = 0; r < 4; ++r) {
      float mx = fmaxf(fmaxf(sfr[0][r], sfr[1][r]), fmaxf(sfr[2][r], sfr[3][r])) * scale;
#pragma unroll
      for (int off = 8; off > 0; off >>= 1) mx = fmaxf(mx, __shfl_xor(mx, off, 16));
      mnew[r] = fmaxf(mrow[r], mx);
      float ps = 0.f;
#pragma unroll
      for (int n = 0; n < 4; ++n) {
        float e = __expf(sfr[n][r] * scale - mnew[r]);
        p[n][r] = e; ps += e;
      }
#pragma unroll
      for (int off = 8; off > 0; off >>= 1) ps += __shfl_xor(ps, off, 16);
      psum[r] = ps;
    }
#pragma unroll
    for (int r = 0; r < 4; ++r) {
      float alpha = __expf(mrow[r] - mnew[r]);
      lrow[r] = lrow[r] * alpha + psum[r];
      mrow[r] = mnew[r];
#pragma unroll
      for (int f = 0; f < 4; ++f) oacc[f][r] *= alpha;
    }
    // P -> per-wave LDS (C-frag layout -> A-frag layout)
#pragma unroll
    for (int n = 0; n < 4; ++n)
#pragma unroll
      for (int r = 0; r < 4; ++r)
        Pl[w][(rgrp + r) * 72 + n * 16 + lr] = (bf16)p[n][r];
    __syncthreads();
    // O += P V
#pragma unroll
    for (int f = 0; f < 4; ++f)
#pragma unroll
      for (int kd = 0; kd < 2; ++kd) {
        bf16x8 aP = *(const bf16x8*)&Pl[w][lr * 72 + kd * 32 + lk];
        bf16x8 bV = *(const bf16x8*)&Vt[(f * 16 + lr) * 72 + kd * 32 + lk];
        oacc[f] = __builtin_amdgcn_mfma_f32_16x16x32_bf16(aP, bV, oacc[f], 0, 0, 0);
      }
  }
#pragma unroll
  for (int f = 0; f < 4; ++f)
#pragma unroll
    for (int r = 0; r < 4; ++r) {
      const int qrow = q0 + rgrp + r;
      attnout[((size_t)(b * NSQ + qrow)) * ND + h * NDH + f * 16 + lr] = oacc[f][r] / lrow[r];
    }
}

// ---------------- LayerNorm (optionally + bf16 residual, + bf16 copy out) ----------------
template <bool RES, bool OUTB>
__global__ __launch_bounds__(256) void ln_kernel(
    const float* __restrict__ x, const bf16* __restrict__ rq,
    const float* __restrict__ g, const float* __restrict__ be,
    float* __restrict__ yf, bf16* __restrict__ yb) {
  __shared__ float sm[4];
  const int row = blockIdx.x, tid = threadIdx.x;
  const size_t base = (size_t)row * ND + tid * 4;
  float4 xv = *(const float4*)(x + base);
  float v0 = xv.x, v1 = xv.y, v2 = xv.z, v3 = xv.w;
  if (RES) {
    union { uint2 u; bf16 h[4]; } q;
    q.u = *(const uint2*)(rq + base);
    v0 += (float)q.h[0]; v1 += (float)q.h[1]; v2 += (float)q.h[2]; v3 += (float)q.h[3];
  }
  float s = v0 + v1 + v2 + v3;
#pragma unroll
  for (int off = 32; off > 0; off >>= 1) s += __shfl_down(s, off, 64);
  if ((tid & 63) == 0) sm[tid >> 6] = s;
  __syncthreads();
  const float mean = (sm[0] + sm[1] + sm[2] + sm[3]) * (1.0f / ND);
  __syncthreads();
  const float d0 = v0 - mean, d1 = v1 - mean, d2 = v2 - mean, d3 = v3 - mean;
  float sq = d0 * d0 + d1 * d1 + d2 * d2 + d3 * d3;
#pragma unroll
  for (int off = 32; off > 0; off >>= 1) sq += __shfl_down(sq, off, 64);
  if ((tid & 63) == 0) sm[tid >> 6] = sq;
  __syncthreads();
  const float var = (sm[0] + sm[1] + sm[2] + sm[3]) * (1.0f / ND);
  const float rs = rsqrtf(var + 1e-5f);
  float4 gv = *(const float4*)(g + tid * 4);
  float4 bv = *(const float4*)(be + tid * 4);
  const float y0 = d0 * rs * gv.x + bv.x;
  const float y1 = d1 * rs * gv.y + bv.y;
  const float y2 = d2 * rs * gv.z + bv.z;
  const float y3 = d3 * rs * gv.w + bv.w;
  *(float4*)(yf + base) = make_float4(y0, y1, y2, y3);
  if (OUTB) {
    union { uint2 u; bf16 h[4]; } o;
    o.h[0] = (bf16)y0; o.h[1] = (bf16)y1; o.h[2] = (bf16)y2; o.h[3] = (bf16)y3;
    *(uint2*)(yb + base) = o.u;
  }
}

extern "C" void kernel_launch(void* const* d_in, const int* in_sizes, int n_in,
                              void* d_out, int out_size, void* d_ws, size_t ws_size,
                              hipStream_t stream) {
  const float* Q  = (const float*)d_in[0];
  const float* K  = (const float*)d_in[1];
  const float* Wq = (const float*)d_in[2];
  const float* bq = (const float*)d_in[3];
  const float* Wk = (const float*)d_in[4];
  const float* bk = (const float*)d_in[5];
  const float* Wv = (const float*)d_in[6];
  const float* bv = (const float*)d_in[7];
  const float* Wo = (const float*)d_in[8];
  const float* bo = (const float*)d_in[9];
  const float* g0 = (const float*)d_in[10];
  const float* b0 = (const float*)d_in[11];
  const float* g1 = (const float*)d_in[12];
  const float* b1 = (const float*)d_in[13];
  float* out = (float*)d_out;

  char* ws = (char*)d_ws;
  const size_t MB = 1024 * 1024;
  bf16* Qb   = (bf16*)(ws + 0);
  bf16* Kb   = (bf16*)(ws + 16 * MB);
  bf16* Wqt  = (bf16*)(ws + 32 * MB);
  bf16* Wkt  = (bf16*)(ws + 34 * MB);
  bf16* Wvt  = (bf16*)(ws + 36 * MB);
  bf16* Wot  = (bf16*)(ws + 38 * MB);
  bf16* qb   = (bf16*)(ws + 40 * MB);
  bf16* kb   = (bf16*)(ws + 56 * MB);
  bf16* vb   = (bf16*)(ws + 72 * MB);
  bf16* vT   = (bf16*)(ws + 88 * MB);
  float* attn = (float*)(ws + 104 * MB);
  float* h0   = (float*)(ws + 0);        // reuse Qb+Kb (dead after qkv GEMMs)
  bf16*  h0b  = (bf16*)(ws + 56 * MB);   // reuse kb  (dead after attention)
  float* out1 = (float*)(ws + 104 * MB); // reuse attn (dead after ln_res)

  // 1. convert inputs to bf16
  cvt_f32_bf16<<<8192, 256, 0, stream>>>(Q, Qb, 2097152);
  cvt_f32_bf16<<<8192, 256, 0, stream>>>(K, Kb, 2097152);
  // 2. weights: transpose + convert
  dim3 tg(16, 16);
  transpose_cvt<<<tg, 256, 0, stream>>>(Wq, Wqt);
  transpose_cvt<<<tg, 256, 0, stream>>>(Wk, Wkt);
  transpose_cvt<<<tg, 256, 0, stream>>>(Wv, Wvt);
  transpose_cvt<<<tg, 256, 0, stream>>>(Wo, Wot);
  // 3. projections
  dim3 gg(8, 64);
  gemm_bt<0><<<gg, 256, 0, stream>>>(Qb, Wqt, bq, qb, nullptr, nullptr, NM, ND, ND);
  gemm_bt<0><<<gg, 256, 0, stream>>>(Kb, Wkt, bk, kb, nullptr, nullptr, NM, ND, ND);
  gemm_bt<0><<<gg, 256, 0, stream>>>(Kb, Wvt, bv, vb, nullptr, nullptr, NM, ND, ND);
  // 4. v -> vT per head
  transpose_v<<<dim3(16, 128), 256, 0, stream>>>(vb, vT);
  // 5. attention
  attn_kernel<<<dim3(16, 128), 256, 0, stream>>>(qb, kb, vT, attn);
  // 6. out0 = LN(q + attn)
  ln_kernel<true, true><<<8192, 256, 0, stream>>>(attn, qb, g0, b0, h0, h0b);
  // 7. out1 = h0 + relu(h0 @ Wo + bo)
  gemm_bt<1><<<gg, 256, 0, stream>>>(h0b, Wot, bo, nullptr, out1, h0, NM, ND, ND);
  // 8. out = LN(out1)
  ln_kernel<false, false><<<8192, 256, 0, stream>>>(out1, nullptr, g1, b1, out, nullptr);
}

// Round 2
// 240.387 us; speedup vs baseline: 1.3343x; 1.3343x over previous
//
#include <hip/hip_runtime.h>
#include <hip/hip_bf16.h>
#include <stdint.h>

// Problem dims
#define NB 8
#define NSQ 1024
#define NSK 1024
#define ND 1024
#define NH 16
#define NDH 64
#define NM (NB * NSQ)   // 8192 rows
#define LOG2E 1.4426950408889634f

typedef __bf16 bf16;
typedef __bf16 bf16x8 __attribute__((ext_vector_type(8)));
typedef float f32x4 __attribute__((ext_vector_type(4)));

// ---------------- async global->LDS (16B per lane) ----------------
__device__ __forceinline__ void async_load16(const void* g, void* l) {
  __builtin_amdgcn_global_load_lds(
      (__attribute__((address_space(1))) void*)g,
      (__attribute__((address_space(3))) void*)l, 16, 0, 0);
}

// ---------------- f32 -> bf16 converter (Q, K) ----------------
__global__ __launch_bounds__(256) void cvt_f32_bf16(const float* __restrict__ in,
                                                    bf16* __restrict__ out, int n4) {
  int i = blockIdx.x * 256 + threadIdx.x;
  if (i < n4) {
    float4 v = *(const float4*)(in + (size_t)i * 4);
    union { uint64_t u; bf16 h[4]; } o;
    o.h[0] = (bf16)v.x; o.h[1] = (bf16)v.y; o.h[2] = (bf16)v.z; o.h[3] = (bf16)v.w;
    *(uint64_t*)(out + (size_t)i * 4) = o.u;
  }
}

// ---------------- W [K,N] f32 -> Wt [N,K] bf16 (tiled transpose) ----------------
__global__ __launch_bounds__(256) void transpose_cvt(const float* __restrict__ W,
                                                     bf16* __restrict__ Wt) {
  __shared__ float t[64][65];
  const int bc = blockIdx.x * 64;
  const int br = blockIdx.y * 64;
  const int tid = threadIdx.x;
  for (int c = tid; c < 1024; c += 256) {
    int r = c >> 4, off = (c & 15) * 4;
    float4 v = *(const float4*)&W[(size_t)(br + r) * 1024 + bc + off];
    t[r][off] = v.x; t[r][off + 1] = v.y; t[r][off + 2] = v.z; t[r][off + 3] = v.w;
  }
  __syncthreads();
  for (int c = tid; c < 512; c += 256) {
    int cc = c >> 3, rr = (c & 7) * 8;
    union { uint4 u; bf16 h[8]; } o;
#pragma unroll
    for (int i = 0; i < 8; ++i) o.h[i] = (bf16)t[rr + i][cc];
    *(uint4*)&Wt[(size_t)(bc + cc) * 1024 + br + rr] = o.u;
  }
}

// ---------------- v [B,SK,D] bf16 -> vT [B,H,DH,SK] bf16 ----------------
__global__ __launch_bounds__(256) void transpose_v(const bf16* __restrict__ vb,
                                                   bf16* __restrict__ vT) {
  const int st = blockIdx.x * 64;
  const int bh = blockIdx.y;
  const int b = bh >> 4, h = bh & 15;
  __shared__ __align__(16) bf16 t[64][72];
  const int tid = threadIdx.x;
  for (int c = tid; c < 512; c += 256) {
    int s = c >> 3, off = (c & 7) * 8;
    *(uint4*)&t[s][off] =
        *(const uint4*)&vb[((size_t)(b * NSK + st + s)) * ND + h * NDH + off];
  }
  __syncthreads();
  for (int c = tid; c < 512; c += 256) {
    int d = c >> 3, s0 = (c & 7) * 8;
    union { uint4 u; bf16 h[8]; } o;
#pragma unroll
    for (int i = 0; i < 8; ++i) o.h[i] = t[s0 + i][d];
    *(uint4*)&vT[((size_t)(bh * NDH + d)) * NSK + st + s0] = o.u;
  }
}

// ---------------- GEMM: C[M,N] = (A[M,K] @ Bt[N,K]^T + bias) * scale ----------------
// MODE 0: Cb = bf16((acc+bias)*scale).  MODE 1: Cb = bf16(Res + relu(acc+bias)).
template <int MODE>
__global__ __launch_bounds__(256) void gemm_bt(
    const bf16* __restrict__ A, const bf16* __restrict__ Bt,
    const float* __restrict__ bias, bf16* __restrict__ Cb,
    const bf16* __restrict__ Resb, float scale,
    int M, int N, int K) {
  __shared__ __align__(16) bf16 As[128 * 32];
  __shared__ __align__(16) bf16 Bs[128 * 32];
  const int tid = threadIdx.x;
  const int bcol = blockIdx.x * 128;
  const int brow = blockIdx.y * 128;
  const int w = tid >> 6, lane = tid & 63;
  const int wm = w >> 1, wn = w & 1;
  const int lr = lane & 15;
  const int lk = (lane >> 4) * 8;
  const int rgrp = (lane >> 4) * 4;

  f32x4 acc[4][4] = {};

  const int c0 = tid, c1 = tid + 256;
  for (int k0 = 0; k0 < K; k0 += 32) {
    __syncthreads();
    async_load16(A + (size_t)(brow + (c0 >> 2)) * K + k0 + (c0 & 3) * 8, &As[c0 * 8]);
    async_load16(A + (size_t)(brow + (c1 >> 2)) * K + k0 + (c1 & 3) * 8, &As[c1 * 8]);
    async_load16(Bt + (size_t)(bcol + (c0 >> 2)) * K + k0 + (c0 & 3) * 8, &Bs[c0 * 8]);
    async_load16(Bt + (size_t)(bcol + (c1 >> 2)) * K + k0 + (c1 & 3) * 8, &Bs[c1 * 8]);
    __syncthreads();
    bf16x8 af[4], bfr[4];
#pragma unroll
    for (int m = 0; m < 4; ++m)
      af[m] = *(const bf16x8*)&As[(wm * 64 + m * 16 + lr) * 32 + lk];
#pragma unroll
    for (int n = 0; n < 4; ++n)
      bfr[n] = *(const bf16x8*)&Bs[(wn * 64 + n * 16 + lr) * 32 + lk];
#pragma unroll
    for (int m = 0; m < 4; ++m)
#pragma unroll
      for (int n = 0; n < 4; ++n)
        acc[m][n] = __builtin_amdgcn_mfma_f32_16x16x32_bf16(af[m], bfr[n], acc[m][n], 0, 0, 0);
  }
#pragma unroll
  for (int m = 0; m < 4; ++m) {
#pragma unroll
    for (int n = 0; n < 4; ++n) {
      const int col = bcol + wn * 64 + n * 16 + lr;
      const float bv = bias[col];
#pragma unroll
      for (int r = 0; r < 4; ++r) {
        const int row = brow + wm * 64 + m * 16 + rgrp + r;
        float v = acc[m][n][r] + bv;
        if (MODE == 0) {
          Cb[(size_t)row * N + col] = (bf16)(v * scale);
        } else {
          float res = (float)Resb[(size_t)row * N + col];
          Cb[(size_t)row * N + col] = (bf16)(res + (v > 0.f ? v : 0.f));
        }
      }
    }
  }
}

// ---------------- fused attention ----------------
// grid: (SQ/256, B*H).  4 waves x 64 q-rows = 256 q per block.
// qb pre-scaled by 1/32, kb pre-scaled by log2(e) => P = exp2(S) = softmax numer, m=0.
// Row-sum via MFMA against ones-fragment. K/V double-buffered via global_load_lds
// with XOR-swizzled source (linear LDS dest), swizzled reads => no bank conflicts.
__global__ __launch_bounds__(256, 2) void attn_kernel(
    const bf16* __restrict__ qb, const bf16* __restrict__ kb,
    const bf16* __restrict__ vT, bf16* __restrict__ attnout) {
  const int bh = blockIdx.y;
  const int b = bh >> 4, h = bh & 15;
  const int tid = threadIdx.x, w = tid >> 6, lane = tid & 63;
  const int lr = lane & 15;
  const int l4 = lane >> 4;
  const int lk = l4 * 8;
  const int rgrp = l4 * 4;
  const int q0 = blockIdx.x * 256 + w * 64;

  __shared__ __align__(16) bf16 Kbuf[2][64 * 64];
  __shared__ __align__(16) bf16 Vbuf[2][64 * 64];
  __shared__ __align__(16) bf16 Pl[4][64 * 72];

  const int sr8 = lane >> 3;   // row within 8-row staging chunk
  const int sg = lane & 7;     // granule
  const int gsw = sg ^ sr8;    // swizzled source granule (rl&7 == sr8)

  bf16x8 aQ[4][2];
#pragma unroll
  for (int grp = 0; grp < 4; ++grp)
#pragma unroll
    for (int kd = 0; kd < 2; ++kd)
      aQ[grp][kd] = *(const bf16x8*)&qb[((size_t)(b * NSQ + q0 + grp * 16 + lr)) * ND +
                                        h * NDH + kd * 32 + lk];

  f32x4 oacc[4][4] = {};
  f32x4 lacc[4] = {};
  bf16x8 ones;
#pragma unroll
  for (int i = 0; i < 8; ++i) ones[i] = (bf16)1.0f;

  const bf16* kbase = kb + (size_t)(b * NSK) * ND + h * NDH;
  const bf16* vbase = vT + (size_t)(bh * NDH) * NSK;

  auto stage = [&](int bi, int kt) {
#pragma unroll
    for (int i = 0; i < 2; ++i) {
      const int rl = w * 16 + i * 8 + sr8;
      async_load16(kbase + (size_t)(kt + rl) * ND + gsw * 8,
                   &Kbuf[bi][(w * 16 + i * 8) * 64]);
      async_load16(vbase + (size_t)rl * NSK + kt + gsw * 8,
                   &Vbuf[bi][(w * 16 + i * 8) * 64]);
    }
  };

  stage(0, 0);

  for (int t = 0; t < 16; ++t) {
    const int bi = t & 1;
    asm volatile("s_waitcnt vmcnt(0)" ::: "memory");
    __syncthreads();
    if (t < 15) stage(bi ^ 1, (t + 1) * 64);

    // K fragments (shared across the 4 q-groups)
    bf16x8 kf[4][2];
#pragma unroll
    for (int n = 0; n < 4; ++n)
#pragma unroll
      for (int kd = 0; kd < 2; ++kd)
        kf[n][kd] = *(const bf16x8*)&Kbuf[bi][(n * 16 + lr) * 64 +
                                              (((kd * 4 + l4) ^ (lr & 7)) * 8)];

    // QK^T + exp2 + P write (no max: scores are small by construction)
#pragma unroll
    for (int grp = 0; grp < 4; ++grp) {
      f32x4 s[4] = {};
#pragma unroll
      for (int kd = 0; kd < 2; ++kd)
#pragma unroll
        for (int n = 0; n < 4; ++n)
          s[n] = __builtin_amdgcn_mfma_f32_16x16x32_bf16(aQ[grp][kd], kf[n][kd], s[n], 0, 0, 0);
#pragma unroll
      for (int n = 0; n < 4; ++n)
#pragma unroll
        for (int r = 0; r < 4; ++r)
          Pl[w][(grp * 16 + rgrp + r) * 72 + n * 16 + lr] =
              (bf16)__builtin_amdgcn_exp2f(s[n][r]);
    }

    // V fragments (shared across q-groups)
    bf16x8 vf[4][2];
#pragma unroll
    for (int f = 0; f < 4; ++f)
#pragma unroll
      for (int kd = 0; kd < 2; ++kd)
        vf[f][kd] = *(const bf16x8*)&Vbuf[bi][(f * 16 + lr) * 64 +
                                              (((kd * 4 + l4) ^ (lr & 7)) * 8)];

    asm volatile("s_waitcnt lgkmcnt(0)" ::: "memory");
    __builtin_amdgcn_sched_barrier(0);

    // O += P V ; l += P * ones
#pragma unroll
    for (int grp = 0; grp < 4; ++grp) {
#pragma unroll
      for (int kd = 0; kd < 2; ++kd) {
        bf16x8 aP = *(const bf16x8*)&Pl[w][(grp * 16 + lr) * 72 + kd * 32 + lk];
#pragma unroll
        for (int f = 0; f < 4; ++f)
          oacc[grp][f] = __builtin_amdgcn_mfma_f32_16x16x32_bf16(aP, vf[f][kd], oacc[grp][f], 0, 0, 0);
        lacc[grp] = __builtin_amdgcn_mfma_f32_16x16x32_bf16(aP, ones, lacc[grp], 0, 0, 0);
      }
    }
  }

#pragma unroll
  for (int grp = 0; grp < 4; ++grp) {
    float inv[4];
#pragma unroll
    for (int r = 0; r < 4; ++r) inv[r] = 1.0f / lacc[grp][r];
#pragma unroll
    for (int f = 0; f < 4; ++f)
#pragma unroll
      for (int r = 0; r < 4; ++r)
        attnout[((size_t)(b * NSQ + q0 + grp * 16 + rgrp + r)) * ND + h * NDH + f * 16 + lr] =
            (bf16)(oacc[grp][f][r] * inv[r]);
  }
}

// ---------------- LayerNorm over bf16 input ----------------
// RES: x + rscale*rq.  OUTF: write f32 (else bf16).
template <bool RES, bool OUTF>
__global__ __launch_bounds__(256) void ln_kernel(
    const bf16* __restrict__ x, const bf16* __restrict__ rq, float rscale,
    const float* __restrict__ g, const float* __restrict__ be,
    bf16* __restrict__ yb, float* __restrict__ yf) {
  __shared__ float sm[4];
  const int row = blockIdx.x, tid = threadIdx.x;
  const size_t base = (size_t)row * ND + tid * 4;
  union { uint2 u; bf16 h[4]; } xv;
  xv.u = *(const uint2*)(x + base);
  float v0 = (float)xv.h[0], v1 = (float)xv.h[1], v2 = (float)xv.h[2], v3 = (float)xv.h[3];
  if (RES) {
    union { uint2 u; bf16 h[4]; } q;
    q.u = *(const uint2*)(rq + base);
    v0 += rscale * (float)q.h[0]; v1 += rscale * (float)q.h[1];
    v2 += rscale * (float)q.h[2]; v3 += rscale * (float)q.h[3];
  }
  float s = v0 + v1 + v2 + v3;
#pragma unroll
  for (int off = 32; off > 0; off >>= 1) s += __shfl_down(s, off, 64);
  if ((tid & 63) == 0) sm[tid >> 6] = s;
  __syncthreads();
  const float mean = (sm[0] + sm[1] + sm[2] + sm[3]) * (1.0f / ND);
  __syncthreads();
  const float d0 = v0 - mean, d1 = v1 - mean, d2 = v2 - mean, d3 = v3 - mean;
  float sq = d0 * d0 + d1 * d1 + d2 * d2 + d3 * d3;
#pragma unroll
  for (int off = 32; off > 0; off >>= 1) sq += __shfl_down(sq, off, 64);
  if ((tid & 63) == 0) sm[tid >> 6] = sq;
  __syncthreads();
  const float var = (sm[0] + sm[1] + sm[2] + sm[3]) * (1.0f / ND);
  const float rs = rsqrtf(var + 1e-5f);
  float4 gv = *(const float4*)(g + tid * 4);
  float4 bv = *(const float4*)(be + tid * 4);
  const float y0 = d0 * rs * gv.x + bv.x;
  const float y1 = d1 * rs * gv.y + bv.y;
  const float y2 = d2 * rs * gv.z + bv.z;
  const float y3 = d3 * rs * gv.w + bv.w;
  if (OUTF) {
    *(float4*)(yf + base) = make_float4(y0, y1, y2, y3);
  } else {
    union { uint2 u; bf16 h[4]; } o;
    o.h[0] = (bf16)y0; o.h[1] = (bf16)y1; o.h[2] = (bf16)y2; o.h[3] = (bf16)y3;
    *(uint2*)(yb + base) = o.u;
  }
}

extern "C" void kernel_launch(void* const* d_in, const int* in_sizes, int n_in,
                              void* d_out, int out_size, void* d_ws, size_t ws_size,
                              hipStream_t stream) {
  const float* Q  = (const float*)d_in[0];
  const float* K  = (const float*)d_in[1];
  const float* Wq = (const float*)d_in[2];
  const float* bq = (const float*)d_in[3];
  const float* Wk = (const float*)d_in[4];
  const float* bk = (const float*)d_in[5];
  const float* Wv = (const float*)d_in[6];
  const float* bv = (const float*)d_in[7];
  const float* Wo = (const float*)d_in[8];
  const float* bo = (const float*)d_in[9];
  const float* g0 = (const float*)d_in[10];
  const float* b0 = (const float*)d_in[11];
  const float* g1 = (const float*)d_in[12];
  const float* b1 = (const float*)d_in[13];
  float* out = (float*)d_out;

  char* ws = (char*)d_ws;
  const size_t MB = 1024 * 1024;
  bf16* Qb    = (bf16*)(ws + 0);
  bf16* Kb    = (bf16*)(ws + 16 * MB);
  bf16* Wqt   = (bf16*)(ws + 32 * MB);
  bf16* Wkt   = (bf16*)(ws + 34 * MB);
  bf16* Wvt   = (bf16*)(ws + 36 * MB);
  bf16* Wot   = (bf16*)(ws + 38 * MB);
  bf16* qb    = (bf16*)(ws + 40 * MB);
  bf16* kb    = (bf16*)(ws + 56 * MB);
  bf16* vb    = (bf16*)(ws + 72 * MB);
  bf16* vT    = (bf16*)(ws + 88 * MB);
  bf16* attnb = (bf16*)(ws + 104 * MB);
  bf16* h0b   = (bf16*)(ws + 56 * MB);   // reuse kb (dead after attention)
  bf16* out1b = (bf16*)(ws + 72 * MB);   // reuse vb (dead after transpose_v)

  // 1. inputs -> bf16
  cvt_f32_bf16<<<8192, 256, 0, stream>>>(Q, Qb, 2097152);
  cvt_f32_bf16<<<8192, 256, 0, stream>>>(K, Kb, 2097152);
  // 2. weights: transpose + convert
  dim3 tg(16, 16);
  transpose_cvt<<<tg, 256, 0, stream>>>(Wq, Wqt);
  transpose_cvt<<<tg, 256, 0, stream>>>(Wk, Wkt);
  transpose_cvt<<<tg, 256, 0, stream>>>(Wv, Wvt);
  transpose_cvt<<<tg, 256, 0, stream>>>(Wo, Wot);
  // 3. projections (scale folding: q *= 1/32 exact; k *= log2e)
  dim3 gg(8, 64);
  gemm_bt<0><<<gg, 256, 0, stream>>>(Qb, Wqt, bq, qb, nullptr, 0.03125f, NM, ND, ND);
  gemm_bt<0><<<gg, 256, 0, stream>>>(Kb, Wkt, bk, kb, nullptr, LOG2E,    NM, ND, ND);
  gemm_bt<0><<<gg, 256, 0, stream>>>(Kb, Wvt, bv, vb, nullptr, 1.0f,     NM, ND, ND);
  // 4. v -> vT per head
  transpose_v<<<dim3(16, 128), 256, 0, stream>>>(vb, vT);
  // 5. attention
  attn_kernel<<<dim3(4, 128), 256, 0, stream>>>(qb, kb, vT, attnb);
  // 6. h0 = LN(32*qb + attn)
  ln_kernel<true, false><<<8192, 256, 0, stream>>>(attnb, qb, 32.0f, g0, b0, h0b, nullptr);
  // 7. out1 = h0 + relu(h0 @ Wo + bo)
  gemm_bt<1><<<gg, 256, 0, stream>>>(h0b, Wot, bo, out1b, h0b, 1.0f, NM, ND, ND);
  // 8. out = LN(out1)
  ln_kernel<false, true><<<8192, 256, 0, stream>>>(out1b, nullptr, 0.f, g1, b1, nullptr, out);
}

// Round 3
// 234.503 us; speedup vs baseline: 1.3678x; 1.0251x over previous
//
#include <hip/hip_runtime.h>
#include <hip/hip_bf16.h>
#include <stdint.h>

// Problem dims
#define NB 8
#define NSQ 1024
#define NSK 1024
#define ND 1024
#define NH 16
#define NDH 64
#define NM (NB * NSQ)   // 8192 rows
#define LOG2E 1.4426950408889634f

typedef __bf16 bf16;
typedef __bf16 bf16x8 __attribute__((ext_vector_type(8)));
typedef float f32x4 __attribute__((ext_vector_type(4)));
typedef float f32x16 __attribute__((ext_vector_type(16)));
typedef unsigned int uint32;

// ---------------- async global->LDS (16B per lane) ----------------
__device__ __forceinline__ void async_load16(const void* g, void* l) {
  __builtin_amdgcn_global_load_lds(
      (__attribute__((address_space(1))) void*)g,
      (__attribute__((address_space(3))) void*)l, 16, 0, 0);
}

// half-swap: x' = {x.lo, y.lo}, y' = {x.hi, y.hi}
__device__ __forceinline__ void permswap(uint32& x, uint32& y) {
#if __has_builtin(__builtin_amdgcn_permlane32_swap)
  auto r = __builtin_amdgcn_permlane32_swap(x, y, false, false);
  x = r[0]; y = r[1];
#else
  asm volatile("v_permlane32_swap_b32 %0, %1" : "+v"(x), "+v"(y));
#endif
}

// ---------------- f32 -> bf16 converter (Q, K) ----------------
__global__ __launch_bounds__(256) void cvt_f32_bf16(const float* __restrict__ in,
                                                    bf16* __restrict__ out, int n4) {
  int i = blockIdx.x * 256 + threadIdx.x;
  if (i < n4) {
    float4 v = *(const float4*)(in + (size_t)i * 4);
    union { uint64_t u; bf16 h[4]; } o;
    o.h[0] = (bf16)v.x; o.h[1] = (bf16)v.y; o.h[2] = (bf16)v.z; o.h[3] = (bf16)v.w;
    *(uint64_t*)(out + (size_t)i * 4) = o.u;
  }
}

// ---------------- W [K,N] f32 -> Wt [N,K] bf16 (tiled transpose) ----------------
__global__ __launch_bounds__(256) void transpose_cvt(const float* __restrict__ W,
                                                     bf16* __restrict__ Wt) {
  __shared__ float t[64][65];
  const int bc = blockIdx.x * 64;
  const int br = blockIdx.y * 64;
  const int tid = threadIdx.x;
  for (int c = tid; c < 1024; c += 256) {
    int r = c >> 4, off = (c & 15) * 4;
    float4 v = *(const float4*)&W[(size_t)(br + r) * 1024 + bc + off];
    t[r][off] = v.x; t[r][off + 1] = v.y; t[r][off + 2] = v.z; t[r][off + 3] = v.w;
  }
  __syncthreads();
  for (int c = tid; c < 512; c += 256) {
    int cc = c >> 3, rr = (c & 7) * 8;
    union { uint4 u; bf16 h[8]; } o;
#pragma unroll
    for (int i = 0; i < 8; ++i) o.h[i] = (bf16)t[rr + i][cc];
    *(uint4*)&Wt[(size_t)(bc + cc) * 1024 + br + rr] = o.u;
  }
}

// ---------------- v (from kvb, stride 2048, offset 1024) -> vT [B,H,DH,SK] ----------------
__global__ __launch_bounds__(256) void transpose_v(const bf16* __restrict__ vsrc,
                                                   bf16* __restrict__ vT) {
  const int st = blockIdx.x * 64;
  const int bh = blockIdx.y;
  const int b = bh >> 4, h = bh & 15;
  __shared__ __align__(16) bf16 t[64][72];
  const int tid = threadIdx.x;
  for (int c = tid; c < 512; c += 256) {
    int s = c >> 3, off = (c & 7) * 8;
    *(uint4*)&t[s][off] =
        *(const uint4*)&vsrc[(size_t)(b * NSK + st + s) * 2048 + 1024 + h * NDH + off];
  }
  __syncthreads();
  for (int c = tid; c < 512; c += 256) {
    int d = c >> 3, s0 = (c & 7) * 8;
    union { uint4 u; bf16 h[8]; } o;
#pragma unroll
    for (int i = 0; i < 8; ++i) o.h[i] = t[s0 + i][d];
    *(uint4*)&vT[((size_t)(bh * NDH + d)) * NSK + st + s0] = o.u;
  }
}

// ---------------- GEMM: C[M,N] = f(A[M,K] @ Bt[N,K]^T) ----------------
// MODE 0: Cb = bf16((acc+bias)*scale)
// MODE 1: Cb = bf16(Res + relu(acc+bias))
// MODE 2: fused KV: col<1024 -> (acc+bias[col])*LOG2E ; else (acc+bias2[col-1024])
template <int MODE>
__global__ __launch_bounds__(256) void gemm_bt(
    const bf16* __restrict__ A, const bf16* __restrict__ Bt,
    const float* __restrict__ bias, const float* __restrict__ bias2,
    bf16* __restrict__ Cb, const bf16* __restrict__ Resb, float scale,
    int M, int N, int K) {
  __shared__ __align__(16) bf16 As[128 * 32];
  __shared__ __align__(16) bf16 Bs[128 * 32];
  const int tid = threadIdx.x;
  const int bcol = blockIdx.x * 128;
  const int brow = blockIdx.y * 128;
  const int w = tid >> 6, lane = tid & 63;
  const int wm = w >> 1, wn = w & 1;
  const int lr = lane & 15;
  const int lk = (lane >> 4) * 8;
  const int rgrp = (lane >> 4) * 4;

  f32x4 acc[4][4] = {};

  const int c0 = tid, c1 = tid + 256;
  for (int k0 = 0; k0 < K; k0 += 32) {
    __syncthreads();
    async_load16(A + (size_t)(brow + (c0 >> 2)) * K + k0 + (c0 & 3) * 8, &As[c0 * 8]);
    async_load16(A + (size_t)(brow + (c1 >> 2)) * K + k0 + (c1 & 3) * 8, &As[c1 * 8]);
    async_load16(Bt + (size_t)(bcol + (c0 >> 2)) * K + k0 + (c0 & 3) * 8, &Bs[c0 * 8]);
    async_load16(Bt + (size_t)(bcol + (c1 >> 2)) * K + k0 + (c1 & 3) * 8, &Bs[c1 * 8]);
    __syncthreads();
    bf16x8 af[4], bfr[4];
#pragma unroll
    for (int m = 0; m < 4; ++m)
      af[m] = *(const bf16x8*)&As[(wm * 64 + m * 16 + lr) * 32 + lk];
#pragma unroll
    for (int n = 0; n < 4; ++n)
      bfr[n] = *(const bf16x8*)&Bs[(wn * 64 + n * 16 + lr) * 32 + lk];
#pragma unroll
    for (int m = 0; m < 4; ++m)
#pragma unroll
      for (int n = 0; n < 4; ++n)
        acc[m][n] = __builtin_amdgcn_mfma_f32_16x16x32_bf16(af[m], bfr[n], acc[m][n], 0, 0, 0);
  }
#pragma unroll
  for (int m = 0; m < 4; ++m) {
#pragma unroll
    for (int n = 0; n < 4; ++n) {
      const int col = bcol + wn * 64 + n * 16 + lr;
      float bv, sc;
      if (MODE == 2) {
        const bool isV = col >= 1024;
        bv = isV ? bias2[col - 1024] : bias[col];
        sc = isV ? 1.0f : LOG2E;
      } else {
        bv = bias[col];
        sc = scale;
      }
#pragma unroll
      for (int r = 0; r < 4; ++r) {
        const int row = brow + wm * 64 + m * 16 + rgrp + r;
        float v = acc[m][n][r] + bv;
        if (MODE == 1) {
          float res = (float)Resb[(size_t)row * N + col];
          Cb[(size_t)row * N + col] = (bf16)(res + (v > 0.f ? v : 0.f));
        } else {
          Cb[(size_t)row * N + col] = (bf16)(v * sc);
        }
      }
    }
  }
}

// ---------------- fused attention: 32x32 MFMA, swapped QK^T, in-register P ----------------
// grid (SQ/256, B*H); 4 waves x 64 q-rows. qb pre-scaled 1/32, k pre-scaled log2e.
// P = exp2(S) (no max subtraction; |S| small by construction). Row sums via ones-MFMA
// on redistributed P A-frags -> same C-layout as O accumulator.
__global__ __launch_bounds__(256, 2) void attn_kernel(
    const bf16* __restrict__ qb, const bf16* __restrict__ kvb,
    const bf16* __restrict__ vT, bf16* __restrict__ attnout) {
  const int bh = blockIdx.y;
  const int b = bh >> 4, h = bh & 15;
  const int tid = threadIdx.x, w = tid >> 6, lane = tid & 63;
  const int l31 = lane & 31;
  const int l1 = lane >> 5;
  const int q0w = blockIdx.x * 256 + w * 64;

  __shared__ __align__(16) bf16 Kl[2][64 * 64];
  __shared__ __align__(16) bf16 Vl[2][64 * 64];

  const int srow = w * 8 + (lane >> 3);        // staging row within 32-row half
  const int gsw = (lane & 7) ^ (lane >> 3);    // pre-swizzled source granule
  const int rg = l31 & 7;                      // read-side swizzle key

  const bf16* kbase = kvb + (size_t)(b * NSK) * 2048 + h * NDH;
  const bf16* vbase = vT + (size_t)(bh * NDH) * NSK;

  // Q fragments (B-operand): lane holds Q[q=l31][d = kd*16 + l1*8 + 0..7]
  bf16x8 qf[2][4];
#pragma unroll
  for (int qs = 0; qs < 2; ++qs)
#pragma unroll
    for (int kd = 0; kd < 4; ++kd)
      qf[qs][kd] = *(const bf16x8*)&qb[(size_t)(b * NSQ + q0w + qs * 32 + l31) * ND +
                                       h * NDH + kd * 16 + l1 * 8];

  f32x16 oacc[2][2] = {};   // [qs][dd]
  f32x16 lacc[2] = {};      // [qs] row-sums (replicated over cols)
  bf16x8 ones;
#pragma unroll
  for (int i = 0; i < 8; ++i) ones[i] = (bf16)1.0f;

  auto stage = [&](int bi, int kt) {
    async_load16(kbase + (size_t)(kt + srow) * 2048 + gsw * 8, &Kl[bi][w * 512]);
    async_load16(kbase + (size_t)(kt + 32 + srow) * 2048 + gsw * 8, &Kl[bi][2048 + w * 512]);
    async_load16(vbase + (size_t)srow * NSK + kt + gsw * 8, &Vl[bi][w * 512]);
    async_load16(vbase + (size_t)(32 + srow) * NSK + kt + gsw * 8, &Vl[bi][2048 + w * 512]);
  };

  stage(0, 0);

  for (int t = 0; t < 16; ++t) {
    const int bi = t & 1;
    asm volatile("s_waitcnt vmcnt(0)" ::: "memory");
    __syncthreads();
    if (t < 15) stage(bi ^ 1, (t + 1) * 64);

    // K A-fragments: lane holds K[key = n*32 + l31][d = kd*16 + l1*8 + 0..7]
    bf16x8 kf[2][4];
#pragma unroll
    for (int n = 0; n < 2; ++n)
#pragma unroll
      for (int kd = 0; kd < 4; ++kd)
        kf[n][kd] = *(const bf16x8*)&Kl[bi][(n * 32 + l31) * 64 + (((kd * 2 + l1) ^ rg) * 8)];

    bf16x8 pa[2][4];  // [qs][kc] P A-fragments
#pragma unroll
    for (int qs = 0; qs < 2; ++qs) {
      f32x16 s0 = {}, s1 = {};
      __builtin_amdgcn_s_setprio(1);
#pragma unroll
      for (int kd = 0; kd < 4; ++kd) {
        s0 = __builtin_amdgcn_mfma_f32_32x32x16_bf16(kf[0][kd], qf[qs][kd], s0, 0, 0, 0);
        s1 = __builtin_amdgcn_mfma_f32_32x32x16_bf16(kf[1][kd], qf[qs][kd], s1, 0, 0, 0);
      }
      __builtin_amdgcn_s_setprio(0);
      // P^T per lane: q = q0w+qs*32+l31, key(n,reg) = 32n + (reg&3) + 8*(reg>>2) + 4*l1
      float e0[16], e1[16];
#pragma unroll
      for (int r = 0; r < 16; ++r) {
        e0[r] = __builtin_amdgcn_exp2f(s0[r]);
        e1[r] = __builtin_amdgcn_exp2f(s1[r]);
      }
      // pack adjacent-key pairs: W[n][r2][p] holds keys 32n + 8r2 + 4*l1 + 2p + {0,1}
      uint32 W[2][4][2];
#pragma unroll
      for (int r2 = 0; r2 < 4; ++r2)
#pragma unroll
        for (int p = 0; p < 2; ++p) {
          uint32 w0, w1;
          asm("v_cvt_pk_bf16_f32 %0, %1, %2"
              : "=v"(w0) : "v"(e0[r2 * 4 + 2 * p]), "v"(e0[r2 * 4 + 2 * p + 1]));
          asm("v_cvt_pk_bf16_f32 %0, %1, %2"
              : "=v"(w1) : "v"(e1[r2 * 4 + 2 * p]), "v"(e1[r2 * 4 + 2 * p + 1]));
          W[0][r2][p] = w0; W[1][r2][p] = w1;
        }
      // redistribute: A-word (kc,j) = W[kc>>1][(kc&1)*2 + l1][j&1] from lane q31+32*(j>>1)
      // one permswap(X=W[..][r2a][p], Y=W[..][r2a+1][p]) yields words j=p and j=p+2.
#pragma unroll
      for (int kc = 0; kc < 4; ++kc) {
        uint32 x0 = W[kc >> 1][(kc & 1) * 2][0], y0 = W[kc >> 1][(kc & 1) * 2 + 1][0];
        uint32 x1 = W[kc >> 1][(kc & 1) * 2][1], y1 = W[kc >> 1][(kc & 1) * 2 + 1][1];
        permswap(x0, y0);
        permswap(x1, y1);
        union { uint32 u[4]; bf16x8 v; } cvt;
        cvt.u[0] = x0; cvt.u[1] = x1; cvt.u[2] = y0; cvt.u[3] = y1;
        pa[qs][kc] = cvt.v;
      }
    }

    // V B-fragments: lane holds V^T[d = dd*32 + l31][k = kc*16 + l1*8 + 0..7]
    bf16x8 vf[2][4];
#pragma unroll
    for (int dd = 0; dd < 2; ++dd)
#pragma unroll
      for (int kc = 0; kc < 4; ++kc)
        vf[dd][kc] = *(const bf16x8*)&Vl[bi][(dd * 32 + l31) * 64 + (((kc * 2 + l1) ^ rg) * 8)];

    __builtin_amdgcn_s_setprio(1);
#pragma unroll
    for (int qs = 0; qs < 2; ++qs)
#pragma unroll
      for (int kc = 0; kc < 4; ++kc) {
        oacc[qs][0] = __builtin_amdgcn_mfma_f32_32x32x16_bf16(pa[qs][kc], vf[0][kc], oacc[qs][0], 0, 0, 0);
        oacc[qs][1] = __builtin_amdgcn_mfma_f32_32x32x16_bf16(pa[qs][kc], vf[1][kc], oacc[qs][1], 0, 0, 0);
        lacc[qs] = __builtin_amdgcn_mfma_f32_32x32x16_bf16(pa[qs][kc], ones, lacc[qs], 0, 0, 0);
      }
    __builtin_amdgcn_s_setprio(0);
  }

  // epilogue: lacc has identical row layout as oacc -> per-reg normalize
#pragma unroll
  for (int qs = 0; qs < 2; ++qs) {
    float inv[16];
#pragma unroll
    for (int r = 0; r < 16; ++r) inv[r] = 1.0f / lacc[qs][r];
#pragma unroll
    for (int dd = 0; dd < 2; ++dd)
#pragma unroll
      for (int r = 0; r < 16; ++r) {
        const int row = q0w + qs * 32 + (r & 3) + 8 * (r >> 2) + 4 * l1;
        attnout[(size_t)(b * NSQ + row) * ND + h * NDH + dd * 32 + l31] =
            (bf16)(oacc[qs][dd][r] * inv[r]);
      }
  }
}

// ---------------- LayerNorm over bf16 input ----------------
template <bool RES, bool OUTF>
__global__ __launch_bounds__(256) void ln_kernel(
    const bf16* __restrict__ x, const bf16* __restrict__ rq, float rscale,
    const float* __restrict__ g, const float* __restrict__ be,
    bf16* __restrict__ yb, float* __restrict__ yf) {
  __shared__ float sm[4];
  const int row = blockIdx.x, tid = threadIdx.x;
  const size_t base = (size_t)row * ND + tid * 4;
  union { uint2 u; bf16 h[4]; } xv;
  xv.u = *(const uint2*)(x + base);
  float v0 = (float)xv.h[0], v1 = (float)xv.h[1], v2 = (float)xv.h[2], v3 = (float)xv.h[3];
  if (RES) {
    union { uint2 u; bf16 h[4]; } q;
    q.u = *(const uint2*)(rq + base);
    v0 += rscale * (float)q.h[0]; v1 += rscale * (float)q.h[1];
    v2 += rscale * (float)q.h[2]; v3 += rscale * (float)q.h[3];
  }
  float s = v0 + v1 + v2 + v3;
#pragma unroll
  for (int off = 32; off > 0; off >>= 1) s += __shfl_down(s, off, 64);
  if ((tid & 63) == 0) sm[tid >> 6] = s;
  __syncthreads();
  const float mean = (sm[0] + sm[1] + sm[2] + sm[3]) * (1.0f / ND);
  __syncthreads();
  const float d0 = v0 - mean, d1 = v1 - mean, d2 = v2 - mean, d3 = v3 - mean;
  float sq = d0 * d0 + d1 * d1 + d2 * d2 + d3 * d3;
#pragma unroll
  for (int off = 32; off > 0; off >>= 1) sq += __shfl_down(sq, off, 64);
  if ((tid & 63) == 0) sm[tid >> 6] = sq;
  __syncthreads();
  const float var = (sm[0] + sm[1] + sm[2] + sm[3]) * (1.0f / ND);
  const float rs = rsqrtf(var + 1e-5f);
  float4 gv = *(const float4*)(g + tid * 4);
  float4 bv = *(const float4*)(be + tid * 4);
  const float y0 = d0 * rs * gv.x + bv.x;
  const float y1 = d1 * rs * gv.y + bv.y;
  const float y2 = d2 * rs * gv.z + bv.z;
  const float y3 = d3 * rs * gv.w + bv.w;
  if (OUTF) {
    *(float4*)(yf + base) = make_float4(y0, y1, y2, y3);
  } else {
    union { uint2 u; bf16 h[4]; } o;
    o.h[0] = (bf16)y0; o.h[1] = (bf16)y1; o.h[2] = (bf16)y2; o.h[3] = (bf16)y3;
    *(uint2*)(yb + base) = o.u;
  }
}

extern "C" void kernel_launch(void* const* d_in, const int* in_sizes, int n_in,
                              void* d_out, int out_size, void* d_ws, size_t ws_size,
                              hipStream_t stream) {
  const float* Q  = (const float*)d_in[0];
  const float* K  = (const float*)d_in[1];
  const float* Wq = (const float*)d_in[2];
  const float* bq = (const float*)d_in[3];
  const float* Wk = (const float*)d_in[4];
  const float* bk = (const float*)d_in[5];
  const float* Wv = (const float*)d_in[6];
  const float* bv = (const float*)d_in[7];
  const float* Wo = (const float*)d_in[8];
  const float* bo = (const float*)d_in[9];
  const float* g0 = (const float*)d_in[10];
  const float* b0 = (const float*)d_in[11];
  const float* g1 = (const float*)d_in[12];
  const float* b1 = (const float*)d_in[13];
  float* out = (float*)d_out;

  char* ws = (char*)d_ws;
  const size_t MB = 1024 * 1024;
  bf16* Qb    = (bf16*)(ws + 0);          // 16MB
  bf16* Kb    = (bf16*)(ws + 16 * MB);    // 16MB
  bf16* Wqt   = (bf16*)(ws + 32 * MB);    // 2MB
  bf16* Wkvt  = (bf16*)(ws + 34 * MB);    // 4MB ([2048][1024])
  bf16* Wot   = (bf16*)(ws + 38 * MB);    // 2MB
  bf16* qb    = (bf16*)(ws + 40 * MB);    // 16MB
  bf16* kvb   = (bf16*)(ws + 56 * MB);    // 32MB ([8192][2048]: k | v)
  bf16* vT    = (bf16*)(ws + 88 * MB);    // 16MB
  bf16* attnb = (bf16*)(ws + 104 * MB);   // 16MB
  bf16* h0b   = (bf16*)(ws + 56 * MB);    // reuse kvb (dead after attn)
  bf16* out1b = (bf16*)(ws + 0);          // reuse Qb (dead after q GEMM)

  // 1. inputs -> bf16
  cvt_f32_bf16<<<8192, 256, 0, stream>>>(Q, Qb, 2097152);
  cvt_f32_bf16<<<8192, 256, 0, stream>>>(K, Kb, 2097152);
  // 2. weights: transpose + convert (Wk,Wv concatenated)
  dim3 tg(16, 16);
  transpose_cvt<<<tg, 256, 0, stream>>>(Wq, Wqt);
  transpose_cvt<<<tg, 256, 0, stream>>>(Wk, Wkvt);
  transpose_cvt<<<tg, 256, 0, stream>>>(Wv, Wkvt + 1024 * 1024);
  transpose_cvt<<<tg, 256, 0, stream>>>(Wo, Wot);
  // 3. projections (q *= 1/32 exact; k *= log2e; v *= 1)
  gemm_bt<0><<<dim3(8, 64), 256, 0, stream>>>(Qb, Wqt, bq, nullptr, qb, nullptr, 0.03125f, NM, ND, ND);
  gemm_bt<2><<<dim3(16, 64), 256, 0, stream>>>(Kb, Wkvt, bk, bv, kvb, nullptr, 1.0f, NM, 2048, ND);
  // 4. v -> vT per head
  transpose_v<<<dim3(16, 128), 256, 0, stream>>>(kvb, vT);
  // 5. attention (normalized bf16 out)
  attn_kernel<<<dim3(4, 128), 256, 0, stream>>>(qb, kvb, vT, attnb);
  // 6. h0 = LN(32*qb + attn)
  ln_kernel<true, false><<<8192, 256, 0, stream>>>(attnb, qb, 32.0f, g0, b0, h0b, nullptr);
  // 7. out1 = h0 + relu(h0 @ Wo + bo)
  gemm_bt<1><<<dim3(8, 64), 256, 0, stream>>>(h0b, Wot, bo, nullptr, out1b, h0b, 1.0f, NM, ND, ND);
  // 8. out = LN(out1)
  ln_kernel<false, true><<<8192, 256, 0, stream>>>(out1b, nullptr, 0.f, g1, b1, nullptr, out);
}

// Round 4
// 206.654 us; speedup vs baseline: 1.5521x; 1.1348x over previous
//
#include <hip/hip_runtime.h>
#include <hip/hip_bf16.h>
#include <stdint.h>

// Problem dims
#define NB 8
#define NSQ 1024
#define NSK 1024
#define ND 1024
#define NH 16
#define NDH 64
#define NM (NB * NSQ)   // 8192 rows
#define LOG2E 1.4426950408889634f

typedef __bf16 bf16;
typedef __bf16 bf16x8 __attribute__((ext_vector_type(8)));
typedef float f32x4 __attribute__((ext_vector_type(4)));
typedef float f32x16 __attribute__((ext_vector_type(16)));
typedef unsigned int uint32;

// ---------------- async global->LDS (16B per lane) ----------------
__device__ __forceinline__ void async_load16(const void* g, void* l) {
  __builtin_amdgcn_global_load_lds(
      (__attribute__((address_space(1))) void*)g,
      (__attribute__((address_space(3))) void*)l, 16, 0, 0);
}

// half-swap: x' = {x.lo, y.lo}, y' = {x.hi, y.hi}
__device__ __forceinline__ void permswap(uint32& x, uint32& y) {
#if __has_builtin(__builtin_amdgcn_permlane32_swap)
  auto r = __builtin_amdgcn_permlane32_swap(x, y, false, false);
  x = r[0]; y = r[1];
#else
  asm volatile("v_permlane32_swap_b32 %0, %1" : "+v"(x), "+v"(y));
#endif
}

// ---------------- f32 -> bf16 converter (Q, K) ----------------
__global__ __launch_bounds__(256) void cvt_f32_bf16(const float* __restrict__ in,
                                                    bf16* __restrict__ out, int n4) {
  int i = blockIdx.x * 256 + threadIdx.x;
  if (i < n4) {
    float4 v = *(const float4*)(in + (size_t)i * 4);
    union { uint64_t u; bf16 h[4]; } o;
    o.h[0] = (bf16)v.x; o.h[1] = (bf16)v.y; o.h[2] = (bf16)v.z; o.h[3] = (bf16)v.w;
    *(uint64_t*)(out + (size_t)i * 4) = o.u;
  }
}

// ---------------- W [K,N] f32 -> Wt [N,K] bf16 (tiled transpose) ----------------
__global__ __launch_bounds__(256) void transpose_cvt(const float* __restrict__ W,
                                                     bf16* __restrict__ Wt) {
  __shared__ float t[64][65];
  const int bc = blockIdx.x * 64;
  const int br = blockIdx.y * 64;
  const int tid = threadIdx.x;
  for (int c = tid; c < 1024; c += 256) {
    int r = c >> 4, off = (c & 15) * 4;
    float4 v = *(const float4*)&W[(size_t)(br + r) * 1024 + bc + off];
    t[r][off] = v.x; t[r][off + 1] = v.y; t[r][off + 2] = v.z; t[r][off + 3] = v.w;
  }
  __syncthreads();
  for (int c = tid; c < 512; c += 256) {
    int cc = c >> 3, rr = (c & 7) * 8;
    union { uint4 u; bf16 h[8]; } o;
#pragma unroll
    for (int i = 0; i < 8; ++i) o.h[i] = (bf16)t[rr + i][cc];
    *(uint4*)&Wt[(size_t)(bc + cc) * 1024 + br + rr] = o.u;
  }
}

// ---------------- v (from kvb, stride 2048, offset 1024) -> vT [B,H,DH,SK] ----------------
__global__ __launch_bounds__(256) void transpose_v(const bf16* __restrict__ vsrc,
                                                   bf16* __restrict__ vT) {
  const int st = blockIdx.x * 64;
  const int bh = blockIdx.y;
  const int b = bh >> 4, h = bh & 15;
  __shared__ __align__(16) bf16 t[64][72];
  const int tid = threadIdx.x;
  for (int c = tid; c < 512; c += 256) {
    int s = c >> 3, off = (c & 7) * 8;
    *(uint4*)&t[s][off] =
        *(const uint4*)&vsrc[(size_t)(b * NSK + st + s) * 2048 + 1024 + h * NDH + off];
  }
  __syncthreads();
  for (int c = tid; c < 512; c += 256) {
    int d = c >> 3, s0 = (c & 7) * 8;
    union { uint4 u; bf16 h[8]; } o;
#pragma unroll
    for (int i = 0; i < 8; ++i) o.h[i] = t[s0 + i][d];
    *(uint4*)&vT[((size_t)(bh * NDH + d)) * NSK + st + s0] = o.u;
  }
}

// ---------------- GEMM: C[M,N] = f(A[M,K] @ Bt[N,K]^T) ----------------
// 128x128 tile, BK=32, double-buffered LDS, 2-deep prefetch, raw barriers,
// counted vmcnt (never 0 in steady state), XCD-aware block swizzle.
// MODE 0: Cb = bf16((acc+bias)*scale)
// MODE 1: Cb = bf16(Res + relu(acc+bias))
// MODE 2: fused KV: col<1024 -> (acc+bias[col])*LOG2E ; else (acc+bias2[col-1024])
template <int MODE>
__global__ __launch_bounds__(256) void gemm_bt(
    const bf16* __restrict__ A, const bf16* __restrict__ Bt,
    const float* __restrict__ bias, const float* __restrict__ bias2,
    bf16* __restrict__ Cb, const bf16* __restrict__ Resb, float scale,
    int M, int N, int K) {
  __shared__ __align__(16) bf16 As[2][128 * 32];
  __shared__ __align__(16) bf16 Bs[2][128 * 32];
  const int tid = threadIdx.x;

  // XCD-aware swizzle (grid size always a multiple of 8 here -> bijective)
  const int nx = gridDim.x;
  const int nwg = nx * gridDim.y;
  const int flat = blockIdx.y * nx + blockIdx.x;
  const int per = nwg >> 3;
  const int xi = (flat & 7) * per + (flat >> 3);
  const int bcol = (xi % nx) * 128;
  const int brow = (xi / nx) * 128;

  const int w = tid >> 6, lane = tid & 63;
  const int wm = w >> 1, wn = w & 1;
  const int lr = lane & 15;
  const int lk = (lane >> 4) * 8;
  const int rgrp = (lane >> 4) * 4;

  f32x4 acc[4][4] = {};

  const int c0 = tid, c1 = tid + 256;
  const bf16* a0p = A + (size_t)(brow + (c0 >> 2)) * K + (c0 & 3) * 8;
  const bf16* a1p = A + (size_t)(brow + (c1 >> 2)) * K + (c1 & 3) * 8;
  const bf16* b0p = Bt + (size_t)(bcol + (c0 >> 2)) * K + (c0 & 3) * 8;
  const bf16* b1p = Bt + (size_t)(bcol + (c1 >> 2)) * K + (c1 & 3) * 8;

  auto stage = [&](int bi, int k0) {
    async_load16(a0p + k0, &As[bi][c0 * 8]);
    async_load16(a1p + k0, &As[bi][c1 * 8]);
    async_load16(b0p + k0, &Bs[bi][c0 * 8]);
    async_load16(b1p + k0, &Bs[bi][c1 * 8]);
  };

  const int NT = K >> 5;
  stage(0, 0);
  stage(1, 32);

  for (int t = 0; t < NT; ++t) {
    const int cur = t & 1;
    // wait for buf[cur]'s 4 loads; keep next tile's 4 in flight
    if (t + 1 < NT) asm volatile("s_waitcnt vmcnt(4)" ::: "memory");
    else            asm volatile("s_waitcnt vmcnt(0)" ::: "memory");
    __builtin_amdgcn_s_barrier();

    bf16x8 af[4], bfr[4];
#pragma unroll
    for (int m = 0; m < 4; ++m)
      af[m] = *(const bf16x8*)&As[cur][(wm * 64 + m * 16 + lr) * 32 + lk];
#pragma unroll
    for (int n = 0; n < 4; ++n)
      bfr[n] = *(const bf16x8*)&Bs[cur][(wn * 64 + n * 16 + lr) * 32 + lk];
    asm volatile("s_waitcnt lgkmcnt(0)" ::: "memory");
    __builtin_amdgcn_sched_barrier(0);
    __builtin_amdgcn_s_barrier();   // all waves done reading buf[cur]

    if (t + 2 < NT) stage(cur, (t + 2) * 32);  // overwrite buf[cur] with tile t+2

    __builtin_amdgcn_s_setprio(1);
#pragma unroll
    for (int m = 0; m < 4; ++m)
#pragma unroll
      for (int n = 0; n < 4; ++n)
        acc[m][n] = __builtin_amdgcn_mfma_f32_16x16x32_bf16(af[m], bfr[n], acc[m][n], 0, 0, 0);
    __builtin_amdgcn_s_setprio(0);
  }

#pragma unroll
  for (int m = 0; m < 4; ++m) {
#pragma unroll
    for (int n = 0; n < 4; ++n) {
      const int col = bcol + wn * 64 + n * 16 + lr;
      float bv, sc;
      if (MODE == 2) {
        const bool isV = col >= 1024;
        bv = isV ? bias2[col - 1024] : bias[col];
        sc = isV ? 1.0f : LOG2E;
      } else {
        bv = bias[col];
        sc = scale;
      }
#pragma unroll
      for (int r = 0; r < 4; ++r) {
        const int row = brow + wm * 64 + m * 16 + rgrp + r;
        float v = acc[m][n][r] + bv;
        if (MODE == 1) {
          float res = (float)Resb[(size_t)row * N + col];
          Cb[(size_t)row * N + col] = (bf16)(res + (v > 0.f ? v : 0.f));
        } else {
          Cb[(size_t)row * N + col] = (bf16)(v * sc);
        }
      }
    }
  }
}

// ---------------- fused attention: 32x32 MFMA, swapped QK^T, in-register P ----------------
__global__ __launch_bounds__(256, 2) void attn_kernel(
    const bf16* __restrict__ qb, const bf16* __restrict__ kvb,
    const bf16* __restrict__ vT, bf16* __restrict__ attnout) {
  const int bh = blockIdx.y;
  const int b = bh >> 4, h = bh & 15;
  const int tid = threadIdx.x, w = tid >> 6, lane = tid & 63;
  const int l31 = lane & 31;
  const int l1 = lane >> 5;
  const int q0w = blockIdx.x * 256 + w * 64;

  __shared__ __align__(16) bf16 Kl[2][64 * 64];
  __shared__ __align__(16) bf16 Vl[2][64 * 64];

  const int srow = w * 8 + (lane >> 3);
  const int gsw = (lane & 7) ^ (lane >> 3);
  const int rg = l31 & 7;

  const bf16* kbase = kvb + (size_t)(b * NSK) * 2048 + h * NDH;
  const bf16* vbase = vT + (size_t)(bh * NDH) * NSK;

  bf16x8 qf[2][4];
#pragma unroll
  for (int qs = 0; qs < 2; ++qs)
#pragma unroll
    for (int kd = 0; kd < 4; ++kd)
      qf[qs][kd] = *(const bf16x8*)&qb[(size_t)(b * NSQ + q0w + qs * 32 + l31) * ND +
                                       h * NDH + kd * 16 + l1 * 8];

  f32x16 oacc[2][2] = {};
  f32x16 lacc[2] = {};
  bf16x8 ones;
#pragma unroll
  for (int i = 0; i < 8; ++i) ones[i] = (bf16)1.0f;

  auto stage = [&](int bi, int kt) {
    async_load16(kbase + (size_t)(kt + srow) * 2048 + gsw * 8, &Kl[bi][w * 512]);
    async_load16(kbase + (size_t)(kt + 32 + srow) * 2048 + gsw * 8, &Kl[bi][2048 + w * 512]);
    async_load16(vbase + (size_t)srow * NSK + kt + gsw * 8, &Vl[bi][w * 512]);
    async_load16(vbase + (size_t)(32 + srow) * NSK + kt + gsw * 8, &Vl[bi][2048 + w * 512]);
  };

  stage(0, 0);

  for (int t = 0; t < 16; ++t) {
    const int bi = t & 1;
    asm volatile("s_waitcnt vmcnt(0)" ::: "memory");
    __syncthreads();
    if (t < 15) stage(bi ^ 1, (t + 1) * 64);

    bf16x8 kf[2][4];
#pragma unroll
    for (int n = 0; n < 2; ++n)
#pragma unroll
      for (int kd = 0; kd < 4; ++kd)
        kf[n][kd] = *(const bf16x8*)&Kl[bi][(n * 32 + l31) * 64 + (((kd * 2 + l1) ^ rg) * 8)];

    bf16x8 pa[2][4];
#pragma unroll
    for (int qs = 0; qs < 2; ++qs) {
      f32x16 s0 = {}, s1 = {};
      __builtin_amdgcn_s_setprio(1);
#pragma unroll
      for (int kd = 0; kd < 4; ++kd) {
        s0 = __builtin_amdgcn_mfma_f32_32x32x16_bf16(kf[0][kd], qf[qs][kd], s0, 0, 0, 0);
        s1 = __builtin_amdgcn_mfma_f32_32x32x16_bf16(kf[1][kd], qf[qs][kd], s1, 0, 0, 0);
      }
      __builtin_amdgcn_s_setprio(0);
      float e0[16], e1[16];
#pragma unroll
      for (int r = 0; r < 16; ++r) {
        e0[r] = __builtin_amdgcn_exp2f(s0[r]);
        e1[r] = __builtin_amdgcn_exp2f(s1[r]);
      }
      uint32 W[2][4][2];
#pragma unroll
      for (int r2 = 0; r2 < 4; ++r2)
#pragma unroll
        for (int p = 0; p < 2; ++p) {
          uint32 w0, w1;
          asm("v_cvt_pk_bf16_f32 %0, %1, %2"
              : "=v"(w0) : "v"(e0[r2 * 4 + 2 * p]), "v"(e0[r2 * 4 + 2 * p + 1]));
          asm("v_cvt_pk_bf16_f32 %0, %1, %2"
              : "=v"(w1) : "v"(e1[r2 * 4 + 2 * p]), "v"(e1[r2 * 4 + 2 * p + 1]));
          W[0][r2][p] = w0; W[1][r2][p] = w1;
        }
#pragma unroll
      for (int kc = 0; kc < 4; ++kc) {
        uint32 x0 = W[kc >> 1][(kc & 1) * 2][0], y0 = W[kc >> 1][(kc & 1) * 2 + 1][0];
        uint32 x1 = W[kc >> 1][(kc & 1) * 2][1], y1 = W[kc >> 1][(kc & 1) * 2 + 1][1];
        permswap(x0, y0);
        permswap(x1, y1);
        union { uint32 u[4]; bf16x8 v; } cvt;
        cvt.u[0] = x0; cvt.u[1] = x1; cvt.u[2] = y0; cvt.u[3] = y1;
        pa[qs][kc] = cvt.v;
      }
    }

    bf16x8 vf[2][4];
#pragma unroll
    for (int dd = 0; dd < 2; ++dd)
#pragma unroll
      for (int kc = 0; kc < 4; ++kc)
        vf[dd][kc] = *(const bf16x8*)&Vl[bi][(dd * 32 + l31) * 64 + (((kc * 2 + l1) ^ rg) * 8)];

    __builtin_amdgcn_s_setprio(1);
#pragma unroll
    for (int qs = 0; qs < 2; ++qs)
#pragma unroll
      for (int kc = 0; kc < 4; ++kc) {
        oacc[qs][0] = __builtin_amdgcn_mfma_f32_32x32x16_bf16(pa[qs][kc], vf[0][kc], oacc[qs][0], 0, 0, 0);
        oacc[qs][1] = __builtin_amdgcn_mfma_f32_32x32x16_bf16(pa[qs][kc], vf[1][kc], oacc[qs][1], 0, 0, 0);
        lacc[qs] = __builtin_amdgcn_mfma_f32_32x32x16_bf16(pa[qs][kc], ones, lacc[qs], 0, 0, 0);
      }
    __builtin_amdgcn_s_setprio(0);
  }

#pragma unroll
  for (int qs = 0; qs < 2; ++qs) {
    float inv[16];
#pragma unroll
    for (int r = 0; r < 16; ++r) inv[r] = 1.0f / lacc[qs][r];
#pragma unroll
    for (int dd = 0; dd < 2; ++dd)
#pragma unroll
      for (int r = 0; r < 16; ++r) {
        const int row = q0w + qs * 32 + (r & 3) + 8 * (r >> 2) + 4 * l1;
        attnout[(size_t)(b * NSQ + row) * ND + h * NDH + dd * 32 + l31] =
            (bf16)(oacc[qs][dd][r] * inv[r]);
      }
  }
}

// ---------------- LayerNorm over bf16 input ----------------
template <bool RES, bool OUTF>
__global__ __launch_bounds__(256) void ln_kernel(
    const bf16* __restrict__ x, const bf16* __restrict__ rq, float rscale,
    const float* __restrict__ g, const float* __restrict__ be,
    bf16* __restrict__ yb, float* __restrict__ yf) {
  __shared__ float sm[4];
  const int row = blockIdx.x, tid = threadIdx.x;
  const size_t base = (size_t)row * ND + tid * 4;
  union { uint2 u; bf16 h[4]; } xv;
  xv.u = *(const uint2*)(x + base);
  float v0 = (float)xv.h[0], v1 = (float)xv.h[1], v2 = (float)xv.h[2], v3 = (float)xv.h[3];
  if (RES) {
    union { uint2 u; bf16 h[4]; } q;
    q.u = *(const uint2*)(rq + base);
    v0 += rscale * (float)q.h[0]; v1 += rscale * (float)q.h[1];
    v2 += rscale * (float)q.h[2]; v3 += rscale * (float)q.h[3];
  }
  float s = v0 + v1 + v2 + v3;
#pragma unroll
  for (int off = 32; off > 0; off >>= 1) s += __shfl_down(s, off, 64);
  if ((tid & 63) == 0) sm[tid >> 6] = s;
  __syncthreads();
  const float mean = (sm[0] + sm[1] + sm[2] + sm[3]) * (1.0f / ND);
  __syncthreads();
  const float d0 = v0 - mean, d1 = v1 - mean, d2 = v2 - mean, d3 = v3 - mean;
  float sq = d0 * d0 + d1 * d1 + d2 * d2 + d3 * d3;
#pragma unroll
  for (int off = 32; off > 0; off >>= 1) sq += __shfl_down(sq, off, 64);
  if ((tid & 63) == 0) sm[tid >> 6] = sq;
  __syncthreads();
  const float var = (sm[0] + sm[1] + sm[2] + sm[3]) * (1.0f / ND);
  const float rs = rsqrtf(var + 1e-5f);
  float4 gv = *(const float4*)(g + tid * 4);
  float4 bv = *(const float4*)(be + tid * 4);
  const float y0 = d0 * rs * gv.x + bv.x;
  const float y1 = d1 * rs * gv.y + bv.y;
  const float y2 = d2 * rs * gv.z + bv.z;
  const float y3 = d3 * rs * gv.w + bv.w;
  if (OUTF) {
    *(float4*)(yf + base) = make_float4(y0, y1, y2, y3);
  } else {
    union { uint2 u; bf16 h[4]; } o;
    o.h[0] = (bf16)y0; o.h[1] = (bf16)y1; o.h[2] = (bf16)y2; o.h[3] = (bf16)y3;
    *(uint2*)(yb + base) = o.u;
  }
}

extern "C" void kernel_launch(void* const* d_in, const int* in_sizes, int n_in,
                              void* d_out, int out_size, void* d_ws, size_t ws_size,
                              hipStream_t stream) {
  const float* Q  = (const float*)d_in[0];
  const float* K  = (const float*)d_in[1];
  const float* Wq = (const float*)d_in[2];
  const float* bq = (const float*)d_in[3];
  const float* Wk = (const float*)d_in[4];
  const float* bk = (const float*)d_in[5];
  const float* Wv = (const float*)d_in[6];
  const float* bv = (const float*)d_in[7];
  const float* Wo = (const float*)d_in[8];
  const float* bo = (const float*)d_in[9];
  const float* g0 = (const float*)d_in[10];
  const float* b0 = (const float*)d_in[11];
  const float* g1 = (const float*)d_in[12];
  const float* b1 = (const float*)d_in[13];
  float* out = (float*)d_out;

  char* ws = (char*)d_ws;
  const size_t MB = 1024 * 1024;
  bf16* Qb    = (bf16*)(ws + 0);          // 16MB
  bf16* Kb    = (bf16*)(ws + 16 * MB);    // 16MB
  bf16* Wqt   = (bf16*)(ws + 32 * MB);    // 2MB
  bf16* Wkvt  = (bf16*)(ws + 34 * MB);    // 4MB ([2048][1024])
  bf16* Wot   = (bf16*)(ws + 38 * MB);    // 2MB
  bf16* qb    = (bf16*)(ws + 40 * MB);    // 16MB
  bf16* kvb   = (bf16*)(ws + 56 * MB);    // 32MB ([8192][2048]: k | v)
  bf16* vT    = (bf16*)(ws + 88 * MB);    // 16MB
  bf16* attnb = (bf16*)(ws + 104 * MB);   // 16MB
  bf16* h0b   = (bf16*)(ws + 56 * MB);    // reuse kvb (dead after attn)
  bf16* out1b = (bf16*)(ws + 0);          // reuse Qb (dead after q GEMM)

  // 1. inputs -> bf16
  cvt_f32_bf16<<<8192, 256, 0, stream>>>(Q, Qb, 2097152);
  cvt_f32_bf16<<<8192, 256, 0, stream>>>(K, Kb, 2097152);
  // 2. weights: transpose + convert (Wk,Wv concatenated)
  dim3 tg(16, 16);
  transpose_cvt<<<tg, 256, 0, stream>>>(Wq, Wqt);
  transpose_cvt<<<tg, 256, 0, stream>>>(Wk, Wkvt);
  transpose_cvt<<<tg, 256, 0, stream>>>(Wv, Wkvt + 1024 * 1024);
  transpose_cvt<<<tg, 256, 0, stream>>>(Wo, Wot);
  // 3. projections (q *= 1/32 exact; k *= log2e; v *= 1)
  gemm_bt<0><<<dim3(8, 64), 256, 0, stream>>>(Qb, Wqt, bq, nullptr, qb, nullptr, 0.03125f, NM, ND, ND);
  gemm_bt<2><<<dim3(16, 64), 256, 0, stream>>>(Kb, Wkvt, bk, bv, kvb, nullptr, 1.0f, NM, 2048, ND);
  // 4. v -> vT per head
  transpose_v<<<dim3(16, 128), 256, 0, stream>>>(kvb, vT);
  // 5. attention (normalized bf16 out)
  attn_kernel<<<dim3(4, 128), 256, 0, stream>>>(qb, kvb, vT, attnb);
  // 6. h0 = LN(32*qb + attn)
  ln_kernel<true, false><<<8192, 256, 0, stream>>>(attnb, qb, 32.0f, g0, b0, h0b, nullptr);
  // 7. out1 = h0 + relu(h0 @ Wo + bo)
  gemm_bt<1><<<dim3(8, 64), 256, 0, stream>>>(h0b, Wot, bo, nullptr, out1b, h0b, 1.0f, NM, ND, ND);
  // 8. out = LN(out1)
  ln_kernel<false, true><<<8192, 256, 0, stream>>>(out1b, nullptr, 0.f, g1, b1, nullptr, out);
}

// Round 5
// 203.669 us; speedup vs baseline: 1.5749x; 1.0147x over previous
//
#include <hip/hip_runtime.h>
#include <hip/hip_bf16.h>
#include <stdint.h>

// Problem dims
#define NB 8
#define NSQ 1024
#define NSK 1024
#define ND 1024
#define NH 16
#define NDH 64
#define NM (NB * NSQ)   // 8192 rows
#define LOG2E 1.4426950408889634f

typedef __bf16 bf16;
typedef __bf16 bf16x8 __attribute__((ext_vector_type(8)));
typedef float f32x4 __attribute__((ext_vector_type(4)));
typedef float f32x16 __attribute__((ext_vector_type(16)));
typedef unsigned int uint32;

// ---------------- async global->LDS (16B per lane) ----------------
__device__ __forceinline__ void async_load16(const void* g, void* l) {
  __builtin_amdgcn_global_load_lds(
      (__attribute__((address_space(1))) void*)g,
      (__attribute__((address_space(3))) void*)l, 16, 0, 0);
}

// half-swap: x' = {x.lo, y.lo}, y' = {x.hi, y.hi}
__device__ __forceinline__ void permswap(uint32& x, uint32& y) {
#if __has_builtin(__builtin_amdgcn_permlane32_swap)
  auto r = __builtin_amdgcn_permlane32_swap(x, y, false, false);
  x = r[0]; y = r[1];
#else
  asm volatile("v_permlane32_swap_b32 %0, %1" : "+v"(x), "+v"(y));
#endif
}

// ---------------- f32 -> bf16 converter (Q, K) ----------------
__global__ __launch_bounds__(256) void cvt_f32_bf16(const float* __restrict__ in,
                                                    bf16* __restrict__ out, int n4) {
  int i = blockIdx.x * 256 + threadIdx.x;
  if (i < n4) {
    float4 v = *(const float4*)(in + (size_t)i * 4);
    union { uint64_t u; bf16 h[4]; } o;
    o.h[0] = (bf16)v.x; o.h[1] = (bf16)v.y; o.h[2] = (bf16)v.z; o.h[3] = (bf16)v.w;
    *(uint64_t*)(out + (size_t)i * 4) = o.u;
  }
}

// ---------------- W [K,N] f32 -> Wt [N,K] bf16 (tiled transpose) ----------------
__global__ __launch_bounds__(256) void transpose_cvt(const float* __restrict__ W,
                                                     bf16* __restrict__ Wt) {
  __shared__ float t[64][65];
  const int bc = blockIdx.x * 64;
  const int br = blockIdx.y * 64;
  const int tid = threadIdx.x;
  for (int c = tid; c < 1024; c += 256) {
    int r = c >> 4, off = (c & 15) * 4;
    float4 v = *(const float4*)&W[(size_t)(br + r) * 1024 + bc + off];
    t[r][off] = v.x; t[r][off + 1] = v.y; t[r][off + 2] = v.z; t[r][off + 3] = v.w;
  }
  __syncthreads();
  for (int c = tid; c < 512; c += 256) {
    int cc = c >> 3, rr = (c & 7) * 8;
    union { uint4 u; bf16 h[8]; } o;
#pragma unroll
    for (int i = 0; i < 8; ++i) o.h[i] = (bf16)t[rr + i][cc];
    *(uint4*)&Wt[(size_t)(bc + cc) * 1024 + br + rr] = o.u;
  }
}

// ---------------- v (from kvb, stride 2048, offset 1024) -> vT [B,H,DH,SK] ----------------
__global__ __launch_bounds__(256) void transpose_v(const bf16* __restrict__ vsrc,
                                                   bf16* __restrict__ vT) {
  const int st = blockIdx.x * 64;
  const int bh = blockIdx.y;
  const int b = bh >> 4, h = bh & 15;
  __shared__ __align__(16) bf16 t[64][72];
  const int tid = threadIdx.x;
  for (int c = tid; c < 512; c += 256) {
    int s = c >> 3, off = (c & 7) * 8;
    *(uint4*)&t[s][off] =
        *(const uint4*)&vsrc[(size_t)(b * NSK + st + s) * 2048 + 1024 + h * NDH + off];
  }
  __syncthreads();
  for (int c = tid; c < 512; c += 256) {
    int d = c >> 3, s0 = (c & 7) * 8;
    union { uint4 u; bf16 h[8]; } o;
#pragma unroll
    for (int i = 0; i < 8; ++i) o.h[i] = t[s0 + i][d];
    *(uint4*)&vT[((size_t)(bh * NDH + d)) * NSK + st + s0] = o.u;
  }
}

// ---------------- GEMM: C[M,N] = f(A[M,K] @ Bt[N,K]^T) ----------------
// 128x128 tile, BK=32, double-buffered LDS, 2-deep prefetch, raw barriers,
// counted vmcnt, XCD swizzle, and granule-XOR LDS swizzle:
//   LDS (row, gphys) holds global granule gphys ^ ((row>>1)&3)  (16B granules)
//   -> fragment reads hit 8 distinct start-banks per quarter-wave (2-way, free).
// MODE 0: Cb = bf16((acc+bias)*scale)
// MODE 1: Cb = bf16(Res + relu(acc+bias))
// MODE 2: fused KV: col<1024 -> (acc+bias[col])*LOG2E ; else (acc+bias2[col-1024])
template <int MODE>
__global__ __launch_bounds__(256) void gemm_bt(
    const bf16* __restrict__ A, const bf16* __restrict__ Bt,
    const float* __restrict__ bias, const float* __restrict__ bias2,
    bf16* __restrict__ Cb, const bf16* __restrict__ Resb, float scale,
    int M, int N, int K) {
  __shared__ __align__(16) bf16 As[2][128 * 32];
  __shared__ __align__(16) bf16 Bs[2][128 * 32];
  const int tid = threadIdx.x;

  // XCD-aware swizzle (grid size always a multiple of 8 here -> bijective)
  const int nx = gridDim.x;
  const int nwg = nx * gridDim.y;
  const int flat = blockIdx.y * nx + blockIdx.x;
  const int per = nwg >> 3;
  const int xi = (flat & 7) * per + (flat >> 3);
  const int bcol = (xi % nx) * 128;
  const int brow = (xi / nx) * 128;

  const int w = tid >> 6, lane = tid & 63;
  const int wm = w >> 1, wn = w & 1;
  const int lr = lane & 15;
  const int l4 = lane >> 4;
  const int rgrp = l4 * 4;
  // swizzled read granule offset (elements)
  const int lkA = ((l4 ^ ((lr >> 1) & 3)) * 8);

  f32x4 acc[4][4] = {};

  const int c0 = tid, c1 = tid + 256;
  // pre-swizzled global source granule: (c&3) ^ ((c>>3)&3)
  const int g0s = (c0 & 3) ^ ((c0 >> 3) & 3);
  const int g1s = (c1 & 3) ^ ((c1 >> 3) & 3);
  const bf16* a0p = A + (size_t)(brow + (c0 >> 2)) * K + g0s * 8;
  const bf16* a1p = A + (size_t)(brow + (c1 >> 2)) * K + g1s * 8;
  const bf16* b0p = Bt + (size_t)(bcol + (c0 >> 2)) * K + g0s * 8;
  const bf16* b1p = Bt + (size_t)(bcol + (c1 >> 2)) * K + g1s * 8;

  auto stage = [&](int bi, int k0) {
    async_load16(a0p + k0, &As[bi][c0 * 8]);
    async_load16(a1p + k0, &As[bi][c1 * 8]);
    async_load16(b0p + k0, &Bs[bi][c0 * 8]);
    async_load16(b1p + k0, &Bs[bi][c1 * 8]);
  };

  const int NT = K >> 5;
  stage(0, 0);
  stage(1, 32);

  for (int t = 0; t < NT; ++t) {
    const int cur = t & 1;
    if (t + 1 < NT) asm volatile("s_waitcnt vmcnt(4)" ::: "memory");
    else            asm volatile("s_waitcnt vmcnt(0)" ::: "memory");
    __builtin_amdgcn_s_barrier();

    bf16x8 af[4], bfr[4];
#pragma unroll
    for (int m = 0; m < 4; ++m)
      af[m] = *(const bf16x8*)&As[cur][(wm * 64 + m * 16 + lr) * 32 + lkA];
#pragma unroll
    for (int n = 0; n < 4; ++n)
      bfr[n] = *(const bf16x8*)&Bs[cur][(wn * 64 + n * 16 + lr) * 32 + lkA];
    asm volatile("s_waitcnt lgkmcnt(0)" ::: "memory");
    __builtin_amdgcn_sched_barrier(0);
    __builtin_amdgcn_s_barrier();   // all waves done reading buf[cur]

    if (t + 2 < NT) stage(cur, (t + 2) * 32);  // overwrite buf[cur] with tile t+2

    __builtin_amdgcn_s_setprio(1);
#pragma unroll
    for (int m = 0; m < 4; ++m)
#pragma unroll
      for (int n = 0; n < 4; ++n)
        acc[m][n] = __builtin_amdgcn_mfma_f32_16x16x32_bf16(af[m], bfr[n], acc[m][n], 0, 0, 0);
    __builtin_amdgcn_s_setprio(0);
  }

#pragma unroll
  for (int m = 0; m < 4; ++m) {
#pragma unroll
    for (int n = 0; n < 4; ++n) {
      const int col = bcol + wn * 64 + n * 16 + lr;
      float bv, sc;
      if (MODE == 2) {
        const bool isV = col >= 1024;
        bv = isV ? bias2[col - 1024] : bias[col];
        sc = isV ? 1.0f : LOG2E;
      } else {
        bv = bias[col];
        sc = scale;
      }
#pragma unroll
      for (int r = 0; r < 4; ++r) {
        const int row = brow + wm * 64 + m * 16 + rgrp + r;
        float v = acc[m][n][r] + bv;
        if (MODE == 1) {
          float res = (float)Resb[(size_t)row * N + col];
          Cb[(size_t)row * N + col] = (bf16)(res + (v > 0.f ? v : 0.f));
        } else {
          Cb[(size_t)row * N + col] = (bf16)(v * sc);
        }
      }
    }
  }
}

// ---------------- fused attention: 32x32 MFMA, swapped QK^T, in-register P ----------------
__global__ __launch_bounds__(256, 2) void attn_kernel(
    const bf16* __restrict__ qb, const bf16* __restrict__ kvb,
    const bf16* __restrict__ vT, bf16* __restrict__ attnout) {
  const int bh = blockIdx.y;
  const int b = bh >> 4, h = bh & 15;
  const int tid = threadIdx.x, w = tid >> 6, lane = tid & 63;
  const int l31 = lane & 31;
  const int l1 = lane >> 5;
  const int q0w = blockIdx.x * 256 + w * 64;

  __shared__ __align__(16) bf16 Kl[2][64 * 64];
  __shared__ __align__(16) bf16 Vl[2][64 * 64];

  const int srow = w * 8 + (lane >> 3);
  const int gsw = (lane & 7) ^ (lane >> 3);
  const int rg = l31 & 7;

  const bf16* kbase = kvb + (size_t)(b * NSK) * 2048 + h * NDH;
  const bf16* vbase = vT + (size_t)(bh * NDH) * NSK;

  bf16x8 qf[2][4];
#pragma unroll
  for (int qs = 0; qs < 2; ++qs)
#pragma unroll
    for (int kd = 0; kd < 4; ++kd)
      qf[qs][kd] = *(const bf16x8*)&qb[(size_t)(b * NSQ + q0w + qs * 32 + l31) * ND +
                                       h * NDH + kd * 16 + l1 * 8];

  f32x16 oacc[2][2] = {};
  f32x16 lacc[2] = {};
  bf16x8 ones;
#pragma unroll
  for (int i = 0; i < 8; ++i) ones[i] = (bf16)1.0f;

  auto stage = [&](int bi, int kt) {
    async_load16(kbase + (size_t)(kt + srow) * 2048 + gsw * 8, &Kl[bi][w * 512]);
    async_load16(kbase + (size_t)(kt + 32 + srow) * 2048 + gsw * 8, &Kl[bi][2048 + w * 512]);
    async_load16(vbase + (size_t)srow * NSK + kt + gsw * 8, &Vl[bi][w * 512]);
    async_load16(vbase + (size_t)(32 + srow) * NSK + kt + gsw * 8, &Vl[bi][2048 + w * 512]);
  };

  stage(0, 0);

  for (int t = 0; t < 16; ++t) {
    const int bi = t & 1;
    asm volatile("s_waitcnt vmcnt(0)" ::: "memory");
    __syncthreads();
    if (t < 15) stage(bi ^ 1, (t + 1) * 64);

    bf16x8 kf[2][4];
#pragma unroll
    for (int n = 0; n < 2; ++n)
#pragma unroll
      for (int kd = 0; kd < 4; ++kd)
        kf[n][kd] = *(const bf16x8*)&Kl[bi][(n * 32 + l31) * 64 + (((kd * 2 + l1) ^ rg) * 8)];

    bf16x8 pa[2][4];
#pragma unroll
    for (int qs = 0; qs < 2; ++qs) {
      f32x16 s0 = {}, s1 = {};
      __builtin_amdgcn_s_setprio(1);
#pragma unroll
      for (int kd = 0; kd < 4; ++kd) {
        s0 = __builtin_amdgcn_mfma_f32_32x32x16_bf16(kf[0][kd], qf[qs][kd], s0, 0, 0, 0);
        s1 = __builtin_amdgcn_mfma_f32_32x32x16_bf16(kf[1][kd], qf[qs][kd], s1, 0, 0, 0);
      }
      __builtin_amdgcn_s_setprio(0);
      float e0[16], e1[16];
#pragma unroll
      for (int r = 0; r < 16; ++r) {
        e0[r] = __builtin_amdgcn_exp2f(s0[r]);
        e1[r] = __builtin_amdgcn_exp2f(s1[r]);
      }
      uint32 W[2][4][2];
#pragma unroll
      for (int r2 = 0; r2 < 4; ++r2)
#pragma unroll
        for (int p = 0; p < 2; ++p) {
          uint32 w0, w1;
          asm("v_cvt_pk_bf16_f32 %0, %1, %2"
              : "=v"(w0) : "v"(e0[r2 * 4 + 2 * p]), "v"(e0[r2 * 4 + 2 * p + 1]));
          asm("v_cvt_pk_bf16_f32 %0, %1, %2"
              : "=v"(w1) : "v"(e1[r2 * 4 + 2 * p]), "v"(e1[r2 * 4 + 2 * p + 1]));
          W[0][r2][p] = w0; W[1][r2][p] = w1;
        }
#pragma unroll
      for (int kc = 0; kc < 4; ++kc) {
        uint32 x0 = W[kc >> 1][(kc & 1) * 2][0], y0 = W[kc >> 1][(kc & 1) * 2 + 1][0];
        uint32 x1 = W[kc >> 1][(kc & 1) * 2][1], y1 = W[kc >> 1][(kc & 1) * 2 + 1][1];
        permswap(x0, y0);
        permswap(x1, y1);
        union { uint32 u[4]; bf16x8 v; } cvt;
        cvt.u[0] = x0; cvt.u[1] = x1; cvt.u[2] = y0; cvt.u[3] = y1;
        pa[qs][kc] = cvt.v;
      }
    }

    bf16x8 vf[2][4];
#pragma unroll
    for (int dd = 0; dd < 2; ++dd)
#pragma unroll
      for (int kc = 0; kc < 4; ++kc)
        vf[dd][kc] = *(const bf16x8*)&Vl[bi][(dd * 32 + l31) * 64 + (((kc * 2 + l1) ^ rg) * 8)];

    __builtin_amdgcn_s_setprio(1);
#pragma unroll
    for (int qs = 0; qs < 2; ++qs)
#pragma unroll
      for (int kc = 0; kc < 4; ++kc) {
        oacc[qs][0] = __builtin_amdgcn_mfma_f32_32x32x16_bf16(pa[qs][kc], vf[0][kc], oacc[qs][0], 0, 0, 0);
        oacc[qs][1] = __builtin_amdgcn_mfma_f32_32x32x16_bf16(pa[qs][kc], vf[1][kc], oacc[qs][1], 0, 0, 0);
        lacc[qs] = __builtin_amdgcn_mfma_f32_32x32x16_bf16(pa[qs][kc], ones, lacc[qs], 0, 0, 0);
      }
    __builtin_amdgcn_s_setprio(0);
  }

#pragma unroll
  for (int qs = 0; qs < 2; ++qs) {
    float inv[16];
#pragma unroll
    for (int r = 0; r < 16; ++r) inv[r] = 1.0f / lacc[qs][r];
#pragma unroll
    for (int dd = 0; dd < 2; ++dd)
#pragma unroll
      for (int r = 0; r < 16; ++r) {
        const int row = q0w + qs * 32 + (r & 3) + 8 * (r >> 2) + 4 * l1;
        attnout[(size_t)(b * NSQ + row) * ND + h * NDH + dd * 32 + l31] =
            (bf16)(oacc[qs][dd][r] * inv[r]);
      }
  }
}

// ---------------- LayerNorm over bf16 input ----------------
template <bool RES, bool OUTF>
__global__ __launch_bounds__(256) void ln_kernel(
    const bf16* __restrict__ x, const bf16* __restrict__ rq, float rscale,
    const float* __restrict__ g, const float* __restrict__ be,
    bf16* __restrict__ yb, float* __restrict__ yf) {
  __shared__ float sm[4];
  const int row = blockIdx.x, tid = threadIdx.x;
  const size_t base = (size_t)row * ND + tid * 4;
  union { uint2 u; bf16 h[4]; } xv;
  xv.u = *(const uint2*)(x + base);
  float v0 = (float)xv.h[0], v1 = (float)xv.h[1], v2 = (float)xv.h[2], v3 = (float)xv.h[3];
  if (RES) {
    union { uint2 u; bf16 h[4]; } q;
    q.u = *(const uint2*)(rq + base);
    v0 += rscale * (float)q.h[0]; v1 += rscale * (float)q.h[1];
    v2 += rscale * (float)q.h[2]; v3 += rscale * (float)q.h[3];
  }
  float s = v0 + v1 + v2 + v3;
#pragma unroll
  for (int off = 32; off > 0; off >>= 1) s += __shfl_down(s, off, 64);
  if ((tid & 63) == 0) sm[tid >> 6] = s;
  __syncthreads();
  const float mean = (sm[0] + sm[1] + sm[2] + sm[3]) * (1.0f / ND);
  __syncthreads();
  const float d0 = v0 - mean, d1 = v1 - mean, d2 = v2 - mean, d3 = v3 - mean;
  float sq = d0 * d0 + d1 * d1 + d2 * d2 + d3 * d3;
#pragma unroll
  for (int off = 32; off > 0; off >>= 1) sq += __shfl_down(sq, off, 64);
  if ((tid & 63) == 0) sm[tid >> 6] = sq;
  __syncthreads();
  const float var = (sm[0] + sm[1] + sm[2] + sm[3]) * (1.0f / ND);
  const float rs = rsqrtf(var + 1e-5f);
  float4 gv = *(const float4*)(g + tid * 4);
  float4 bv = *(const float4*)(be + tid * 4);
  const float y0 = d0 * rs * gv.x + bv.x;
  const float y1 = d1 * rs * gv.y + bv.y;
  const float y2 = d2 * rs * gv.z + bv.z;
  const float y3 = d3 * rs * gv.w + bv.w;
  if (OUTF) {
    *(float4*)(yf + base) = make_float4(y0, y1, y2, y3);
  } else {
    union { uint2 u; bf16 h[4]; } o;
    o.h[0] = (bf16)y0; o.h[1] = (bf16)y1; o.h[2] = (bf16)y2; o.h[3] = (bf16)y3;
    *(uint2*)(yb + base) = o.u;
  }
}

extern "C" void kernel_launch(void* const* d_in, const int* in_sizes, int n_in,
                              void* d_out, int out_size, void* d_ws, size_t ws_size,
                              hipStream_t stream) {
  const float* Q  = (const float*)d_in[0];
  const float* K  = (const float*)d_in[1];
  const float* Wq = (const float*)d_in[2];
  const float* bq = (const float*)d_in[3];
  const float* Wk = (const float*)d_in[4];
  const float* bk = (const float*)d_in[5];
  const float* Wv = (const float*)d_in[6];
  const float* bv = (const float*)d_in[7];
  const float* Wo = (const float*)d_in[8];
  const float* bo = (const float*)d_in[9];
  const float* g0 = (const float*)d_in[10];
  const float* b0 = (const float*)d_in[11];
  const float* g1 = (const float*)d_in[12];
  const float* b1 = (const float*)d_in[13];
  float* out = (float*)d_out;

  char* ws = (char*)d_ws;
  const size_t MB = 1024 * 1024;
  bf16* Qb    = (bf16*)(ws + 0);          // 16MB
  bf16* Kb    = (bf16*)(ws + 16 * MB);    // 16MB
  bf16* Wqt   = (bf16*)(ws + 32 * MB);    // 2MB
  bf16* Wkvt  = (bf16*)(ws + 34 * MB);    // 4MB ([2048][1024])
  bf16* Wot   = (bf16*)(ws + 38 * MB);    // 2MB
  bf16* qb    = (bf16*)(ws + 40 * MB);    // 16MB
  bf16* kvb   = (bf16*)(ws + 56 * MB);    // 32MB ([8192][2048]: k | v)
  bf16* vT    = (bf16*)(ws + 88 * MB);    // 16MB
  bf16* attnb = (bf16*)(ws + 104 * MB);   // 16MB
  bf16* h0b   = (bf16*)(ws + 56 * MB);    // reuse kvb (dead after attn)
  bf16* out1b = (bf16*)(ws + 0);          // reuse Qb (dead after q GEMM)

  // 1. inputs -> bf16
  cvt_f32_bf16<<<8192, 256, 0, stream>>>(Q, Qb, 2097152);
  cvt_f32_bf16<<<8192, 256, 0, stream>>>(K, Kb, 2097152);
  // 2. weights: transpose + convert (Wk,Wv concatenated)
  dim3 tg(16, 16);
  transpose_cvt<<<tg, 256, 0, stream>>>(Wq, Wqt);
  transpose_cvt<<<tg, 256, 0, stream>>>(Wk, Wkvt);
  transpose_cvt<<<tg, 256, 0, stream>>>(Wv, Wkvt + 1024 * 1024);
  transpose_cvt<<<tg, 256, 0, stream>>>(Wo, Wot);
  // 3. projections (q *= 1/32 exact; k *= log2e; v *= 1)
  gemm_bt<0><<<dim3(8, 64), 256, 0, stream>>>(Qb, Wqt, bq, nullptr, qb, nullptr, 0.03125f, NM, ND, ND);
  gemm_bt<2><<<dim3(16, 64), 256, 0, stream>>>(Kb, Wkvt, bk, bv, kvb, nullptr, 1.0f, NM, 2048, ND);
  // 4. v -> vT per head
  transpose_v<<<dim3(16, 128), 256, 0, stream>>>(kvb, vT);
  // 5. attention (normalized bf16 out)
  attn_kernel<<<dim3(4, 128), 256, 0, stream>>>(qb, kvb, vT, attnb);
  // 6. h0 = LN(32*qb + attn)
  ln_kernel<true, false><<<8192, 256, 0, stream>>>(attnb, qb, 32.0f, g0, b0, h0b, nullptr);
  // 7. out1 = h0 + relu(h0 @ Wo + bo)
  gemm_bt<1><<<dim3(8, 64), 256, 0, stream>>>(h0b, Wot, bo, nullptr, out1b, h0b, 1.0f, NM, ND, ND);
  // 8. out = LN(out1)
  ln_kernel<false, true><<<8192, 256, 0, stream>>>(out1b, nullptr, 0.f, g1, b1, nullptr, out);
}

// Round 6
// 195.028 us; speedup vs baseline: 1.6447x; 1.0443x over previous
//
#include <hip/hip_runtime.h>
#include <hip/hip_bf16.h>
#include <stdint.h>

// Problem dims
#define NB 8
#define NSQ 1024
#define NSK 1024
#define ND 1024
#define NH 16
#define NDH 64
#define NM (NB * NSQ)   // 8192 rows
#define LOG2E 1.4426950408889634f

typedef __bf16 bf16;
typedef __bf16 bf16x8 __attribute__((ext_vector_type(8)));
typedef float f32x4 __attribute__((ext_vector_type(4)));
typedef float f32x16 __attribute__((ext_vector_type(16)));
typedef unsigned int uint32;

// ---------------- async global->LDS (16B per lane) ----------------
__device__ __forceinline__ void async_load16(const void* g, void* l) {
  __builtin_amdgcn_global_load_lds(
      (__attribute__((address_space(1))) void*)g,
      (__attribute__((address_space(3))) void*)l, 16, 0, 0);
}

// half-swap: x' = {x.lo, y.lo}, y' = {x.hi, y.hi}
__device__ __forceinline__ void permswap(uint32& x, uint32& y) {
#if __has_builtin(__builtin_amdgcn_permlane32_swap)
  auto r = __builtin_amdgcn_permlane32_swap(x, y, false, false);
  x = r[0]; y = r[1];
#else
  asm volatile("v_permlane32_swap_b32 %0, %1" : "+v"(x), "+v"(y));
#endif
}

// ---------------- f32 -> bf16 converter (Q, K) ----------------
__global__ __launch_bounds__(256) void cvt_f32_bf16(const float* __restrict__ in,
                                                    bf16* __restrict__ out, int n4) {
  int i = blockIdx.x * 256 + threadIdx.x;
  if (i < n4) {
    float4 v = *(const float4*)(in + (size_t)i * 4);
    union { uint64_t u; bf16 h[4]; } o;
    o.h[0] = (bf16)v.x; o.h[1] = (bf16)v.y; o.h[2] = (bf16)v.z; o.h[3] = (bf16)v.w;
    *(uint64_t*)(out + (size_t)i * 4) = o.u;
  }
}

// ---------------- W [K,N] f32 -> Wt [N,K] bf16 (tiled transpose) ----------------
__global__ __launch_bounds__(256) void transpose_cvt(const float* __restrict__ W,
                                                     bf16* __restrict__ Wt) {
  __shared__ float t[64][65];
  const int bc = blockIdx.x * 64;
  const int br = blockIdx.y * 64;
  const int tid = threadIdx.x;
  for (int c = tid; c < 1024; c += 256) {
    int r = c >> 4, off = (c & 15) * 4;
    float4 v = *(const float4*)&W[(size_t)(br + r) * 1024 + bc + off];
    t[r][off] = v.x; t[r][off + 1] = v.y; t[r][off + 2] = v.z; t[r][off + 3] = v.w;
  }
  __syncthreads();
  for (int c = tid; c < 512; c += 256) {
    int cc = c >> 3, rr = (c & 7) * 8;
    union { uint4 u; bf16 h[8]; } o;
#pragma unroll
    for (int i = 0; i < 8; ++i) o.h[i] = (bf16)t[rr + i][cc];
    *(uint4*)&Wt[(size_t)(bc + cc) * 1024 + br + rr] = o.u;
  }
}

// ---------------- v (from kvb, stride 2048, offset 1024) -> vT [B,H,DH,SK] ----------------
__global__ __launch_bounds__(256) void transpose_v(const bf16* __restrict__ vsrc,
                                                   bf16* __restrict__ vT) {
  const int st = blockIdx.x * 64;
  const int bh = blockIdx.y;
  const int b = bh >> 4, h = bh & 15;
  __shared__ __align__(16) bf16 t[64][72];
  const int tid = threadIdx.x;
  for (int c = tid; c < 512; c += 256) {
    int s = c >> 3, off = (c & 7) * 8;
    *(uint4*)&t[s][off] =
        *(const uint4*)&vsrc[(size_t)(b * NSK + st + s) * 2048 + 1024 + h * NDH + off];
  }
  __syncthreads();
  for (int c = tid; c < 512; c += 256) {
    int d = c >> 3, s0 = (c & 7) * 8;
    union { uint4 u; bf16 h[8]; } o;
#pragma unroll
    for (int i = 0; i < 8; ++i) o.h[i] = t[s0 + i][d];
    *(uint4*)&vT[((size_t)(bh * NDH + d)) * NSK + st + s0] = o.u;
  }
}

// ---------------- 8-phase GEMM: C[M,N] = f(A[M,K=1024] @ Bt[N,K]^T) ----------------
// BM x 256 tile, BK=64, 8 waves (2x4), 2-dbuf LDS, 4 phases/K-tile, counted vmcnt(2)
// (never 0 in steady state), granule-XOR LDS swizzle (write-side pre-swizzled source,
// read-side XOR), XCD-aware block swizzle.
// MODE 0: Cb = bf16((acc+bias)*scale)
// MODE 1: Cb = bf16(Res + relu(acc+bias))
// MODE 2: fused KV (N=2048): tile col<1024 -> (acc+bk)*LOG2E ; else (acc+bv)
template <int BM, int MODE, int NX>
__global__ __launch_bounds__(512, 2) void gemm8p(
    const bf16* __restrict__ A, const bf16* __restrict__ Bt,
    const float* __restrict__ bias, const float* __restrict__ bias2,
    bf16* __restrict__ Cb, const bf16* __restrict__ Resb, float scale, int N) {
  constexpr int RA = BM / 64;   // A stage rounds (4 or 2); B always 4
  constexpr int NT = 16;        // K = 1024 = 16 x 64
  constexpr int MR = BM / 32;   // per-wave m-frags (8 or 4)
  __shared__ __align__(16) bf16 As[2][BM * 64];
  __shared__ __align__(16) bf16 Bs[2][256 * 64];

  const int tid = threadIdx.x;
  const int flat = blockIdx.x;
  const int nwg = gridDim.x;
  const int xi = (flat & 7) * (nwg >> 3) + (flat >> 3);   // XCD swizzle (nwg%8==0)
  const int bcol = (xi & (NX - 1)) * 256;
  const int brow = (xi / NX) * BM;

  const int w = tid >> 6, lane = tid & 63;
  const int wm = w >> 2, wn = w & 3;                      // 2 x 4 waves
  const int lr = lane & 15, l4 = lane >> 4;
  const int rgrp = l4 * 4;
  const int rk = lr & 7;

  // staging: thread tid covers row (r*64 + tid>>3), dest granule tid&7,
  // source granule pre-swizzled so LDS(row, g) = global(row, g ^ (row&7)).
  const int rowoff = tid >> 3;
  const int gsrc = (tid & 7) ^ ((tid >> 3) & 7);
  const bf16* Ag = A + (size_t)(brow + rowoff) * 1024 + gsrc * 8;
  const bf16* Bg = Bt + (size_t)(bcol + rowoff) * 1024 + gsrc * 8;
  const int lds_o = rowoff * 64 + (tid & 7) * 8;

  auto stA = [&](int d, int r, int kt) {
    async_load16(Ag + (size_t)r * (64 * 1024) + kt * 64, &As[d][r * 4096 + lds_o]);
  };
  auto stB = [&](int d, int r, int kt) {
    async_load16(Bg + (size_t)r * (64 * 1024) + kt * 64, &Bs[d][r * 4096 + lds_o]);
  };
  auto fA = [&](int d, int mrow, int ks) {
    return *(const bf16x8*)&As[d][(mrow + lr) * 64 + (((ks * 4 + l4) ^ rk) * 8)];
  };
  auto fB = [&](int d, int nrow, int ks) {
    return *(const bf16x8*)&Bs[d][(nrow + lr) * 64 + (((ks * 4 + l4) ^ rk) * 8)];
  };

  f32x4 acc[MR][4] = {};
  bf16x8 af[4][2], bfr[4][2];

  // prologue: K-tile 0 fully + K-tile 1 A-rounds 0,1
#pragma unroll
  for (int r = 0; r < RA; ++r) stA(0, r, 0);
#pragma unroll
  for (int r = 0; r < 4; ++r) stB(0, r, 0);
  stA(1, 0, 1);
  stA(1, 1, 1);
  asm volatile("s_waitcnt vmcnt(2)" ::: "memory");   // K-tile 0 landed
  __builtin_amdgcn_s_barrier();

  for (int t = 0; t < NT; ++t) {
    const int cur = t & 1, nxt = cur ^ 1;
    // ================= phase 1 =================
#pragma unroll
    for (int i = 0; i < 4; ++i) {
      af[i][0] = fA(cur, wm * (BM / 2) + i * 16, 0);
      af[i][1] = fA(cur, wm * (BM / 2) + i * 16, 1);
    }
#pragma unroll
    for (int j = 0; j < 2; ++j) {
      bfr[j][0] = fB(cur, wn * 64 + j * 16, 0);
      bfr[j][1] = fB(cur, wn * 64 + j * 16, 1);
    }
    if (t + 1 < NT) {
      if constexpr (BM == 256) { stA(nxt, 2, t + 1); stA(nxt, 3, t + 1); }
      else                     { stB(nxt, 0, t + 1); stB(nxt, 1, t + 1); }
    }
    __builtin_amdgcn_s_barrier();
    asm volatile("s_waitcnt lgkmcnt(0)" ::: "memory");
    __builtin_amdgcn_sched_barrier(0);
    __builtin_amdgcn_s_setprio(1);
    if constexpr (BM == 256) {
#pragma unroll
      for (int i = 0; i < 4; ++i)
#pragma unroll
        for (int j = 0; j < 2; ++j)
#pragma unroll
          for (int ks = 0; ks < 2; ++ks)
            acc[i][j] = __builtin_amdgcn_mfma_f32_16x16x32_bf16(af[i][ks], bfr[j][ks], acc[i][j], 0, 0, 0);
    } else {
#pragma unroll
      for (int i = 0; i < 4; ++i)
#pragma unroll
        for (int ks = 0; ks < 2; ++ks)
          acc[i][0] = __builtin_amdgcn_mfma_f32_16x16x32_bf16(af[i][ks], bfr[0][ks], acc[i][0], 0, 0, 0);
    }
    __builtin_amdgcn_s_setprio(0);
    __builtin_amdgcn_s_barrier();
    // ================= phase 2 =================
#pragma unroll
    for (int j = 2; j < 4; ++j) {
      bfr[j][0] = fB(cur, wn * 64 + j * 16, 0);
      bfr[j][1] = fB(cur, wn * 64 + j * 16, 1);
    }
    if (t + 1 < NT) {
      if constexpr (BM == 256) { stB(nxt, 0, t + 1); stB(nxt, 1, t + 1); }
      else                     { stB(nxt, 2, t + 1); stB(nxt, 3, t + 1); }
    }
    __builtin_amdgcn_s_barrier();
    asm volatile("s_waitcnt lgkmcnt(0)" ::: "memory");
    __builtin_amdgcn_sched_barrier(0);
    __builtin_amdgcn_s_setprio(1);
    if constexpr (BM == 256) {
#pragma unroll
      for (int i = 0; i < 4; ++i)
#pragma unroll
        for (int j = 2; j < 4; ++j)
#pragma unroll
          for (int ks = 0; ks < 2; ++ks)
            acc[i][j] = __builtin_amdgcn_mfma_f32_16x16x32_bf16(af[i][ks], bfr[j][ks], acc[i][j], 0, 0, 0);
    } else {
#pragma unroll
      for (int i = 0; i < 4; ++i)
#pragma unroll
        for (int ks = 0; ks < 2; ++ks)
          acc[i][1] = __builtin_amdgcn_mfma_f32_16x16x32_bf16(af[i][ks], bfr[1][ks], acc[i][1], 0, 0, 0);
    }
    __builtin_amdgcn_s_setprio(0);
    __builtin_amdgcn_s_barrier();
    // ================= phase 3 =================
    if constexpr (BM == 256) {
#pragma unroll
      for (int i = 0; i < 4; ++i) {
        af[i][0] = fA(cur, wm * 128 + 64 + i * 16, 0);
        af[i][1] = fA(cur, wm * 128 + 64 + i * 16, 1);
      }
      if (t + 1 < NT) { stB(nxt, 2, t + 1); stB(nxt, 3, t + 1); }
    }
    __builtin_amdgcn_s_barrier();
    if constexpr (BM == 256) {
      asm volatile("s_waitcnt lgkmcnt(0)" ::: "memory");
      __builtin_amdgcn_sched_barrier(0);
    }
    __builtin_amdgcn_s_setprio(1);
    if constexpr (BM == 256) {
#pragma unroll
      for (int i = 0; i < 4; ++i)
#pragma unroll
        for (int j = 0; j < 2; ++j)
#pragma unroll
          for (int ks = 0; ks < 2; ++ks)
            acc[4 + i][j] = __builtin_amdgcn_mfma_f32_16x16x32_bf16(af[i][ks], bfr[j][ks], acc[4 + i][j], 0, 0, 0);
    } else {
#pragma unroll
      for (int i = 0; i < 4; ++i)
#pragma unroll
        for (int ks = 0; ks < 2; ++ks)
          acc[i][2] = __builtin_amdgcn_mfma_f32_16x16x32_bf16(af[i][ks], bfr[2][ks], acc[i][2], 0, 0, 0);
    }
    __builtin_amdgcn_s_setprio(0);
    __builtin_amdgcn_s_barrier();
    // ================= phase 4 =================
    if (t + 2 < NT) { stA(cur, 0, t + 2); stA(cur, 1, t + 2); }
    __builtin_amdgcn_s_barrier();
    __builtin_amdgcn_s_setprio(1);
    if constexpr (BM == 256) {
#pragma unroll
      for (int i = 0; i < 4; ++i)
#pragma unroll
        for (int j = 2; j < 4; ++j)
#pragma unroll
          for (int ks = 0; ks < 2; ++ks)
            acc[4 + i][j] = __builtin_amdgcn_mfma_f32_16x16x32_bf16(af[i][ks], bfr[j][ks], acc[4 + i][j], 0, 0, 0);
    } else {
#pragma unroll
      for (int i = 0; i < 4; ++i)
#pragma unroll
        for (int ks = 0; ks < 2; ++ks)
          acc[i][3] = __builtin_amdgcn_mfma_f32_16x16x32_bf16(af[i][ks], bfr[3][ks], acc[i][3], 0, 0, 0);
    }
    __builtin_amdgcn_s_setprio(0);
    if (t + 1 < NT) {  // next K-tile fully landed; keep K-tile t+2's 2 loads in flight
      if (t + 2 < NT) asm volatile("s_waitcnt vmcnt(2)" ::: "memory");
      else            asm volatile("s_waitcnt vmcnt(0)" ::: "memory");
    }
    __builtin_amdgcn_s_barrier();
  }

  // ---------------- epilogue ----------------
#pragma unroll
  for (int m = 0; m < MR; ++m) {
#pragma unroll
    for (int n = 0; n < 4; ++n) {
      const int col = bcol + wn * 64 + n * 16 + lr;
      float bv, sc;
      if (MODE == 2) {
        const bool isV = (bcol >= 1024);   // tile-uniform (256 | 1024)
        bv = isV ? bias2[col - 1024] : bias[col];
        sc = isV ? 1.0f : LOG2E;
      } else {
        bv = bias[col];
        sc = scale;
      }
#pragma unroll
      for (int r = 0; r < 4; ++r) {
        const int row = brow + wm * (BM / 2) + m * 16 + rgrp + r;
        float v = acc[m][n][r] + bv;
        if (MODE == 1) {
          float res = (float)Resb[(size_t)row * N + col];
          Cb[(size_t)row * N + col] = (bf16)(res + (v > 0.f ? v : 0.f));
        } else {
          Cb[(size_t)row * N + col] = (bf16)(v * sc);
        }
      }
    }
  }
}

// ---------------- fused attention: 32x32 MFMA, swapped QK^T, in-register P ----------------
__global__ __launch_bounds__(256, 2) void attn_kernel(
    const bf16* __restrict__ qb, const bf16* __restrict__ kvb,
    const bf16* __restrict__ vT, bf16* __restrict__ attnout) {
  const int bh = blockIdx.y;
  const int b = bh >> 4, h = bh & 15;
  const int tid = threadIdx.x, w = tid >> 6, lane = tid & 63;
  const int l31 = lane & 31;
  const int l1 = lane >> 5;
  const int q0w = blockIdx.x * 256 + w * 64;

  __shared__ __align__(16) bf16 Kl[2][64 * 64];
  __shared__ __align__(16) bf16 Vl[2][64 * 64];

  const int srow = w * 8 + (lane >> 3);
  const int gsw = (lane & 7) ^ (lane >> 3);
  const int rg = l31 & 7;

  const bf16* kbase = kvb + (size_t)(b * NSK) * 2048 + h * NDH;
  const bf16* vbase = vT + (size_t)(bh * NDH) * NSK;

  bf16x8 qf[2][4];
#pragma unroll
  for (int qs = 0; qs < 2; ++qs)
#pragma unroll
    for (int kd = 0; kd < 4; ++kd)
      qf[qs][kd] = *(const bf16x8*)&qb[(size_t)(b * NSQ + q0w + qs * 32 + l31) * ND +
                                       h * NDH + kd * 16 + l1 * 8];

  f32x16 oacc[2][2] = {};
  f32x16 lacc[2] = {};
  bf16x8 ones;
#pragma unroll
  for (int i = 0; i < 8; ++i) ones[i] = (bf16)1.0f;

  auto stage = [&](int bi, int kt) {
    async_load16(kbase + (size_t)(kt + srow) * 2048 + gsw * 8, &Kl[bi][w * 512]);
    async_load16(kbase + (size_t)(kt + 32 + srow) * 2048 + gsw * 8, &Kl[bi][2048 + w * 512]);
    async_load16(vbase + (size_t)srow * NSK + kt + gsw * 8, &Vl[bi][w * 512]);
    async_load16(vbase + (size_t)(32 + srow) * NSK + kt + gsw * 8, &Vl[bi][2048 + w * 512]);
  };

  stage(0, 0);

  for (int t = 0; t < 16; ++t) {
    const int bi = t & 1;
    asm volatile("s_waitcnt vmcnt(0)" ::: "memory");
    __syncthreads();
    if (t < 15) stage(bi ^ 1, (t + 1) * 64);

    bf16x8 kf[2][4];
#pragma unroll
    for (int n = 0; n < 2; ++n)
#pragma unroll
      for (int kd = 0; kd < 4; ++kd)
        kf[n][kd] = *(const bf16x8*)&Kl[bi][(n * 32 + l31) * 64 + (((kd * 2 + l1) ^ rg) * 8)];

    bf16x8 pa[2][4];
#pragma unroll
    for (int qs = 0; qs < 2; ++qs) {
      f32x16 s0 = {}, s1 = {};
      __builtin_amdgcn_s_setprio(1);
#pragma unroll
      for (int kd = 0; kd < 4; ++kd) {
        s0 = __builtin_amdgcn_mfma_f32_32x32x16_bf16(kf[0][kd], qf[qs][kd], s0, 0, 0, 0);
        s1 = __builtin_amdgcn_mfma_f32_32x32x16_bf16(kf[1][kd], qf[qs][kd], s1, 0, 0, 0);
      }
      __builtin_amdgcn_s_setprio(0);
      float e0[16], e1[16];
#pragma unroll
      for (int r = 0; r < 16; ++r) {
        e0[r] = __builtin_amdgcn_exp2f(s0[r]);
        e1[r] = __builtin_amdgcn_exp2f(s1[r]);
      }
      uint32 W[2][4][2];
#pragma unroll
      for (int r2 = 0; r2 < 4; ++r2)
#pragma unroll
        for (int p = 0; p < 2; ++p) {
          uint32 w0, w1;
          asm("v_cvt_pk_bf16_f32 %0, %1, %2"
              : "=v"(w0) : "v"(e0[r2 * 4 + 2 * p]), "v"(e0[r2 * 4 + 2 * p + 1]));
          asm("v_cvt_pk_bf16_f32 %0, %1, %2"
              : "=v"(w1) : "v"(e1[r2 * 4 + 2 * p]), "v"(e1[r2 * 4 + 2 * p + 1]));
          W[0][r2][p] = w0; W[1][r2][p] = w1;
        }
#pragma unroll
      for (int kc = 0; kc < 4; ++kc) {
        uint32 x0 = W[kc >> 1][(kc & 1) * 2][0], y0 = W[kc >> 1][(kc & 1) * 2 + 1][0];
        uint32 x1 = W[kc >> 1][(kc & 1) * 2][1], y1 = W[kc >> 1][(kc & 1) * 2 + 1][1];
        permswap(x0, y0);
        permswap(x1, y1);
        union { uint32 u[4]; bf16x8 v; } cvt;
        cvt.u[0] = x0; cvt.u[1] = x1; cvt.u[2] = y0; cvt.u[3] = y1;
        pa[qs][kc] = cvt.v;
      }
    }

    bf16x8 vf[2][4];
#pragma unroll
    for (int dd = 0; dd < 2; ++dd)
#pragma unroll
      for (int kc = 0; kc < 4; ++kc)
        vf[dd][kc] = *(const bf16x8*)&Vl[bi][(dd * 32 + l31) * 64 + (((kc * 2 + l1) ^ rg) * 8)];

    __builtin_amdgcn_s_setprio(1);
#pragma unroll
    for (int qs = 0; qs < 2; ++qs)
#pragma unroll
      for (int kc = 0; kc < 4; ++kc) {
        oacc[qs][0] = __builtin_amdgcn_mfma_f32_32x32x16_bf16(pa[qs][kc], vf[0][kc], oacc[qs][0], 0, 0, 0);
        oacc[qs][1] = __builtin_amdgcn_mfma_f32_32x32x16_bf16(pa[qs][kc], vf[1][kc], oacc[qs][1], 0, 0, 0);
        lacc[qs] = __builtin_amdgcn_mfma_f32_32x32x16_bf16(pa[qs][kc], ones, lacc[qs], 0, 0, 0);
      }
    __builtin_amdgcn_s_setprio(0);
  }

#pragma unroll
  for (int qs = 0; qs < 2; ++qs) {
    float inv[16];
#pragma unroll
    for (int r = 0; r < 16; ++r) inv[r] = 1.0f / lacc[qs][r];
#pragma unroll
    for (int dd = 0; dd < 2; ++dd)
#pragma unroll
      for (int r = 0; r < 16; ++r) {
        const int row = q0w + qs * 32 + (r & 3) + 8 * (r >> 2) + 4 * l1;
        attnout[(size_t)(b * NSQ + row) * ND + h * NDH + dd * 32 + l31] =
            (bf16)(oacc[qs][dd][r] * inv[r]);
      }
  }
}

// ---------------- LayerNorm over bf16 input ----------------
template <bool RES, bool OUTF>
__global__ __launch_bounds__(256) void ln_kernel(
    const bf16* __restrict__ x, const bf16* __restrict__ rq, float rscale,
    const float* __restrict__ g, const float* __restrict__ be,
    bf16* __restrict__ yb, float* __restrict__ yf) {
  __shared__ float sm[4];
  const int row = blockIdx.x, tid = threadIdx.x;
  const size_t base = (size_t)row * ND + tid * 4;
  union { uint2 u; bf16 h[4]; } xv;
  xv.u = *(const uint2*)(x + base);
  float v0 = (float)xv.h[0], v1 = (float)xv.h[1], v2 = (float)xv.h[2], v3 = (float)xv.h[3];
  if (RES) {
    union { uint2 u; bf16 h[4]; } q;
    q.u = *(const uint2*)(rq + base);
    v0 += rscale * (float)q.h[0]; v1 += rscale * (float)q.h[1];
    v2 += rscale * (float)q.h[2]; v3 += rscale * (float)q.h[3];
  }
  float s = v0 + v1 + v2 + v3;
#pragma unroll
  for (int off = 32; off > 0; off >>= 1) s += __shfl_down(s, off, 64);
  if ((tid & 63) == 0) sm[tid >> 6] = s;
  __syncthreads();
  const float mean = (sm[0] + sm[1] + sm[2] + sm[3]) * (1.0f / ND);
  __syncthreads();
  const float d0 = v0 - mean, d1 = v1 - mean, d2 = v2 - mean, d3 = v3 - mean;
  float sq = d0 * d0 + d1 * d1 + d2 * d2 + d3 * d3;
#pragma unroll
  for (int off = 32; off > 0; off >>= 1) sq += __shfl_down(sq, off, 64);
  if ((tid & 63) == 0) sm[tid >> 6] = sq;
  __syncthreads();
  const float var = (sm[0] + sm[1] + sm[2] + sm[3]) * (1.0f / ND);
  const float rs = rsqrtf(var + 1e-5f);
  float4 gv = *(const float4*)(g + tid * 4);
  float4 bv = *(const float4*)(be + tid * 4);
  const float y0 = d0 * rs * gv.x + bv.x;
  const float y1 = d1 * rs * gv.y + bv.y;
  const float y2 = d2 * rs * gv.z + bv.z;
  const float y3 = d3 * rs * gv.w + bv.w;
  if (OUTF) {
    *(float4*)(yf + base) = make_float4(y0, y1, y2, y3);
  } else {
    union { uint2 u; bf16 h[4]; } o;
    o.h[0] = (bf16)y0; o.h[1] = (bf16)y1; o.h[2] = (bf16)y2; o.h[3] = (bf16)y3;
    *(uint2*)(yb + base) = o.u;
  }
}

extern "C" void kernel_launch(void* const* d_in, const int* in_sizes, int n_in,
                              void* d_out, int out_size, void* d_ws, size_t ws_size,
                              hipStream_t stream) {
  const float* Q  = (const float*)d_in[0];
  const float* K  = (const float*)d_in[1];
  const float* Wq = (const float*)d_in[2];
  const float* bq = (const float*)d_in[3];
  const float* Wk = (const float*)d_in[4];
  const float* bk = (const float*)d_in[5];
  const float* Wv = (const float*)d_in[6];
  const float* bv = (const float*)d_in[7];
  const float* Wo = (const float*)d_in[8];
  const float* bo = (const float*)d_in[9];
  const float* g0 = (const float*)d_in[10];
  const float* b0 = (const float*)d_in[11];
  const float* g1 = (const float*)d_in[12];
  const float* b1 = (const float*)d_in[13];
  float* out = (float*)d_out;

  char* ws = (char*)d_ws;
  const size_t MB = 1024 * 1024;
  bf16* Qb    = (bf16*)(ws + 0);          // 16MB
  bf16* Kb    = (bf16*)(ws + 16 * MB);    // 16MB
  bf16* Wqt   = (bf16*)(ws + 32 * MB);    // 2MB
  bf16* Wkvt  = (bf16*)(ws + 34 * MB);    // 4MB ([2048][1024])
  bf16* Wot   = (bf16*)(ws + 38 * MB);    // 2MB
  bf16* qb    = (bf16*)(ws + 40 * MB);    // 16MB
  bf16* kvb   = (bf16*)(ws + 56 * MB);    // 32MB ([8192][2048]: k | v)
  bf16* vT    = (bf16*)(ws + 88 * MB);    // 16MB
  bf16* attnb = (bf16*)(ws + 104 * MB);   // 16MB
  bf16* h0b   = (bf16*)(ws + 56 * MB);    // reuse kvb (dead after attn)
  bf16* out1b = (bf16*)(ws + 0);          // reuse Qb (dead after q GEMM)

  // 1. inputs -> bf16
  cvt_f32_bf16<<<8192, 256, 0, stream>>>(Q, Qb, 2097152);
  cvt_f32_bf16<<<8192, 256, 0, stream>>>(K, Kb, 2097152);
  // 2. weights: transpose + convert (Wk,Wv concatenated)
  dim3 tg(16, 16);
  transpose_cvt<<<tg, 256, 0, stream>>>(Wq, Wqt);
  transpose_cvt<<<tg, 256, 0, stream>>>(Wk, Wkvt);
  transpose_cvt<<<tg, 256, 0, stream>>>(Wv, Wkvt + 1024 * 1024);
  transpose_cvt<<<tg, 256, 0, stream>>>(Wo, Wot);
  // 3. projections (q *= 1/32 exact; k *= log2e; v *= 1)
  gemm8p<256, 2, 8><<<256, 512, 0, stream>>>(Kb, Wkvt, bk, bv, kvb, nullptr, 1.0f, 2048);
  gemm8p<128, 0, 4><<<256, 512, 0, stream>>>(Qb, Wqt, bq, nullptr, qb, nullptr, 0.03125f, 1024);
  // 4. v -> vT per head
  transpose_v<<<dim3(16, 128), 256, 0, stream>>>(kvb, vT);
  // 5. attention (normalized bf16 out)
  attn_kernel<<<dim3(4, 128), 256, 0, stream>>>(qb, kvb, vT, attnb);
  // 6. h0 = LN(32*qb + attn)
  ln_kernel<true, false><<<8192, 256, 0, stream>>>(attnb, qb, 32.0f, g0, b0, h0b, nullptr);
  // 7. out1 = h0 + relu(h0 @ Wo + bo)
  gemm8p<128, 1, 4><<<256, 512, 0, stream>>>(h0b, Wot, bo, nullptr, out1b, h0b, 1.0f, 1024);
  // 8. out = LN(out1)
  ln_kernel<false, true><<<8192, 256, 0, stream>>>(out1b, nullptr, 0.f, g1, b1, nullptr, out);
}

// Round 7
// 182.087 us; speedup vs baseline: 1.7616x; 1.0711x over previous
//
#include <hip/hip_runtime.h>
#include <hip/hip_bf16.h>
#include <stdint.h>

// Problem dims
#define NB 8
#define NSQ 1024
#define NSK 1024
#define ND 1024
#define NH 16
#define NDH 64
#define NM (NB * NSQ)   // 8192 rows
#define LOG2E 1.4426950408889634f

typedef __bf16 bf16;
typedef __bf16 bf16x8 __attribute__((ext_vector_type(8)));
typedef float f32x4 __attribute__((ext_vector_type(4)));
typedef float f32x16 __attribute__((ext_vector_type(16)));
typedef unsigned int uint32;

// ---------------- async global->LDS (16B per lane) ----------------
__device__ __forceinline__ void async_load16(const void* g, void* l) {
  __builtin_amdgcn_global_load_lds(
      (__attribute__((address_space(1))) void*)g,
      (__attribute__((address_space(3))) void*)l, 16, 0, 0);
}

// half-swap: x' = {x.lo, y.lo}, y' = {x.hi, y.hi}
__device__ __forceinline__ void permswap(uint32& x, uint32& y) {
#if __has_builtin(__builtin_amdgcn_permlane32_swap)
  auto r = __builtin_amdgcn_permlane32_swap(x, y, false, false);
  x = r[0]; y = r[1];
#else
  asm volatile("v_permlane32_swap_b32 %0, %1" : "+v"(x), "+v"(y));
#endif
}

// ---------------- f32 -> bf16 converter (Q and K fused, grid.y selects) ----------------
__global__ __launch_bounds__(256) void cvt2_f32_bf16(const float* __restrict__ A,
                                                     const float* __restrict__ B,
                                                     bf16* __restrict__ Oa,
                                                     bf16* __restrict__ Ob) {
  const float* in = blockIdx.y ? B : A;
  bf16* out = blockIdx.y ? Ob : Oa;
  int i = blockIdx.x * 256 + threadIdx.x;
  float4 v = *(const float4*)(in + (size_t)i * 4);
  union { uint64_t u; bf16 h[4]; } o;
  o.h[0] = (bf16)v.x; o.h[1] = (bf16)v.y; o.h[2] = (bf16)v.z; o.h[3] = (bf16)v.w;
  *(uint64_t*)(out + (size_t)i * 4) = o.u;
}

// ---------------- 4x W [K,N] f32 -> Wt [N,K] bf16 (fused, grid.z selects) ----------------
__global__ __launch_bounds__(256) void transpose_cvt4(
    const float* __restrict__ W0, const float* __restrict__ W1,
    const float* __restrict__ W2, const float* __restrict__ W3,
    bf16* __restrict__ O0, bf16* __restrict__ O1,
    bf16* __restrict__ O2, bf16* __restrict__ O3) {
  const float* W; bf16* Wt;
  switch (blockIdx.z) {
    case 0: W = W0; Wt = O0; break;
    case 1: W = W1; Wt = O1; break;
    case 2: W = W2; Wt = O2; break;
    default: W = W3; Wt = O3; break;
  }
  __shared__ float t[64][65];
  const int bc = blockIdx.x * 64;
  const int br = blockIdx.y * 64;
  const int tid = threadIdx.x;
  for (int c = tid; c < 1024; c += 256) {
    int r = c >> 4, off = (c & 15) * 4;
    float4 v = *(const float4*)&W[(size_t)(br + r) * 1024 + bc + off];
    t[r][off] = v.x; t[r][off + 1] = v.y; t[r][off + 2] = v.z; t[r][off + 3] = v.w;
  }
  __syncthreads();
  for (int c = tid; c < 512; c += 256) {
    int cc = c >> 3, rr = (c & 7) * 8;
    union { uint4 u; bf16 h[8]; } o;
#pragma unroll
    for (int i = 0; i < 8; ++i) o.h[i] = (bf16)t[rr + i][cc];
    *(uint4*)&Wt[(size_t)(bc + cc) * 1024 + br + rr] = o.u;
  }
}

// ---------------- v (from kvb, stride 2048, offset 1024) -> vT [B,H,DH,SK] ----------------
__global__ __launch_bounds__(256) void transpose_v(const bf16* __restrict__ vsrc,
                                                   bf16* __restrict__ vT) {
  const int st = blockIdx.x * 64;
  const int bh = blockIdx.y;
  const int b = bh >> 4, h = bh & 15;
  __shared__ __align__(16) bf16 t[64][72];
  const int tid = threadIdx.x;
  for (int c = tid; c < 512; c += 256) {
    int s = c >> 3, off = (c & 7) * 8;
    *(uint4*)&t[s][off] =
        *(const uint4*)&vsrc[(size_t)(b * NSK + st + s) * 2048 + 1024 + h * NDH + off];
  }
  __syncthreads();
  for (int c = tid; c < 512; c += 256) {
    int d = c >> 3, s0 = (c & 7) * 8;
    union { uint4 u; bf16 h[8]; } o;
#pragma unroll
    for (int i = 0; i < 8; ++i) o.h[i] = t[s0 + i][d];
    *(uint4*)&vT[((size_t)(bh * NDH + d)) * NSK + st + s0] = o.u;
  }
}

// ---------------- 8-phase GEMM: C[M,N] = f(A[M,K=1024] @ Bt[N,K]^T) ----------------
template <int BM, int MODE, int NX>
__global__ __launch_bounds__(512, 2) void gemm8p(
    const bf16* __restrict__ A, const bf16* __restrict__ Bt,
    const float* __restrict__ bias, const float* __restrict__ bias2,
    bf16* __restrict__ Cb, const bf16* __restrict__ Resb, float scale, int N) {
  constexpr int RA = BM / 64;
  constexpr int NT = 16;
  constexpr int MR = BM / 32;
  __shared__ __align__(16) bf16 As[2][BM * 64];
  __shared__ __align__(16) bf16 Bs[2][256 * 64];

  const int tid = threadIdx.x;
  const int flat = blockIdx.x;
  const int nwg = gridDim.x;
  const int xi = (flat & 7) * (nwg >> 3) + (flat >> 3);
  const int bcol = (xi & (NX - 1)) * 256;
  const int brow = (xi / NX) * BM;

  const int w = tid >> 6, lane = tid & 63;
  const int wm = w >> 2, wn = w & 3;
  const int lr = lane & 15, l4 = lane >> 4;
  const int rgrp = l4 * 4;
  const int rk = lr & 7;

  const int rowoff = tid >> 3;
  const int gsrc = (tid & 7) ^ ((tid >> 3) & 7);
  const bf16* Ag = A + (size_t)(brow + rowoff) * 1024 + gsrc * 8;
  const bf16* Bg = Bt + (size_t)(bcol + rowoff) * 1024 + gsrc * 8;
  const int lds_o = rowoff * 64 + (tid & 7) * 8;

  auto stA = [&](int d, int r, int kt) {
    async_load16(Ag + (size_t)r * (64 * 1024) + kt * 64, &As[d][r * 4096 + lds_o]);
  };
  auto stB = [&](int d, int r, int kt) {
    async_load16(Bg + (size_t)r * (64 * 1024) + kt * 64, &Bs[d][r * 4096 + lds_o]);
  };
  auto fA = [&](int d, int mrow, int ks) {
    return *(const bf16x8*)&As[d][(mrow + lr) * 64 + (((ks * 4 + l4) ^ rk) * 8)];
  };
  auto fB = [&](int d, int nrow, int ks) {
    return *(const bf16x8*)&Bs[d][(nrow + lr) * 64 + (((ks * 4 + l4) ^ rk) * 8)];
  };

  f32x4 acc[MR][4] = {};
  bf16x8 af[4][2], bfr[4][2];

#pragma unroll
  for (int r = 0; r < RA; ++r) stA(0, r, 0);
#pragma unroll
  for (int r = 0; r < 4; ++r) stB(0, r, 0);
  stA(1, 0, 1);
  stA(1, 1, 1);
  asm volatile("s_waitcnt vmcnt(2)" ::: "memory");
  __builtin_amdgcn_s_barrier();

  for (int t = 0; t < NT; ++t) {
    const int cur = t & 1, nxt = cur ^ 1;
    // ================= phase 1 =================
#pragma unroll
    for (int i = 0; i < 4; ++i) {
      af[i][0] = fA(cur, wm * (BM / 2) + i * 16, 0);
      af[i][1] = fA(cur, wm * (BM / 2) + i * 16, 1);
    }
#pragma unroll
    for (int j = 0; j < 2; ++j) {
      bfr[j][0] = fB(cur, wn * 64 + j * 16, 0);
      bfr[j][1] = fB(cur, wn * 64 + j * 16, 1);
    }
    if (t + 1 < NT) {
      if constexpr (BM == 256) { stA(nxt, 2, t + 1); stA(nxt, 3, t + 1); }
      else                     { stB(nxt, 0, t + 1); stB(nxt, 1, t + 1); }
    }
    __builtin_amdgcn_s_barrier();
    asm volatile("s_waitcnt lgkmcnt(0)" ::: "memory");
    __builtin_amdgcn_sched_barrier(0);
    __builtin_amdgcn_s_setprio(1);
    if constexpr (BM == 256) {
#pragma unroll
      for (int i = 0; i < 4; ++i)
#pragma unroll
        for (int j = 0; j < 2; ++j)
#pragma unroll
          for (int ks = 0; ks < 2; ++ks)
            acc[i][j] = __builtin_amdgcn_mfma_f32_16x16x32_bf16(af[i][ks], bfr[j][ks], acc[i][j], 0, 0, 0);
    } else {
#pragma unroll
      for (int i = 0; i < 4; ++i)
#pragma unroll
        for (int ks = 0; ks < 2; ++ks)
          acc[i][0] = __builtin_amdgcn_mfma_f32_16x16x32_bf16(af[i][ks], bfr[0][ks], acc[i][0], 0, 0, 0);
    }
    __builtin_amdgcn_s_setprio(0);
    __builtin_amdgcn_s_barrier();
    // ================= phase 2 =================
#pragma unroll
    for (int j = 2; j < 4; ++j) {
      bfr[j][0] = fB(cur, wn * 64 + j * 16, 0);
      bfr[j][1] = fB(cur, wn * 64 + j * 16, 1);
    }
    if (t + 1 < NT) {
      if constexpr (BM == 256) { stB(nxt, 0, t + 1); stB(nxt, 1, t + 1); }
      else                     { stB(nxt, 2, t + 1); stB(nxt, 3, t + 1); }
    }
    __builtin_amdgcn_s_barrier();
    asm volatile("s_waitcnt lgkmcnt(0)" ::: "memory");
    __builtin_amdgcn_sched_barrier(0);
    __builtin_amdgcn_s_setprio(1);
    if constexpr (BM == 256) {
#pragma unroll
      for (int i = 0; i < 4; ++i)
#pragma unroll
        for (int j = 2; j < 4; ++j)
#pragma unroll
          for (int ks = 0; ks < 2; ++ks)
            acc[i][j] = __builtin_amdgcn_mfma_f32_16x16x32_bf16(af[i][ks], bfr[j][ks], acc[i][j], 0, 0, 0);
    } else {
#pragma unroll
      for (int i = 0; i < 4; ++i)
#pragma unroll
        for (int ks = 0; ks < 2; ++ks)
          acc[i][1] = __builtin_amdgcn_mfma_f32_16x16x32_bf16(af[i][ks], bfr[1][ks], acc[i][1], 0, 0, 0);
    }
    __builtin_amdgcn_s_setprio(0);
    __builtin_amdgcn_s_barrier();
    // ================= phase 3 =================
    if constexpr (BM == 256) {
#pragma unroll
      for (int i = 0; i < 4; ++i) {
        af[i][0] = fA(cur, wm * 128 + 64 + i * 16, 0);
        af[i][1] = fA(cur, wm * 128 + 64 + i * 16, 1);
      }
      if (t + 1 < NT) { stB(nxt, 2, t + 1); stB(nxt, 3, t + 1); }
    }
    __builtin_amdgcn_s_barrier();
    if constexpr (BM == 256) {
      asm volatile("s_waitcnt lgkmcnt(0)" ::: "memory");
      __builtin_amdgcn_sched_barrier(0);
    }
    __builtin_amdgcn_s_setprio(1);
    if constexpr (BM == 256) {
#pragma unroll
      for (int i = 0; i < 4; ++i)
#pragma unroll
        for (int j = 0; j < 2; ++j)
#pragma unroll
          for (int ks = 0; ks < 2; ++ks)
            acc[4 + i][j] = __builtin_amdgcn_mfma_f32_16x16x32_bf16(af[i][ks], bfr[j][ks], acc[4 + i][j], 0, 0, 0);
    } else {
#pragma unroll
      for (int i = 0; i < 4; ++i)
#pragma unroll
        for (int ks = 0; ks < 2; ++ks)
          acc[i][2] = __builtin_amdgcn_mfma_f32_16x16x32_bf16(af[i][ks], bfr[2][ks], acc[i][2], 0, 0, 0);
    }
    __builtin_amdgcn_s_setprio(0);
    __builtin_amdgcn_s_barrier();
    // ================= phase 4 =================
    if (t + 2 < NT) { stA(cur, 0, t + 2); stA(cur, 1, t + 2); }
    __builtin_amdgcn_s_barrier();
    __builtin_amdgcn_s_setprio(1);
    if constexpr (BM == 256) {
#pragma unroll
      for (int i = 0; i < 4; ++i)
#pragma unroll
        for (int j = 2; j < 4; ++j)
#pragma unroll
          for (int ks = 0; ks < 2; ++ks)
            acc[4 + i][j] = __builtin_amdgcn_mfma_f32_16x16x32_bf16(af[i][ks], bfr[j][ks], acc[4 + i][j], 0, 0, 0);
    } else {
#pragma unroll
      for (int i = 0; i < 4; ++i)
#pragma unroll
        for (int ks = 0; ks < 2; ++ks)
          acc[i][3] = __builtin_amdgcn_mfma_f32_16x16x32_bf16(af[i][ks], bfr[3][ks], acc[i][3], 0, 0, 0);
    }
    __builtin_amdgcn_s_setprio(0);
    if (t + 1 < NT) {
      if (t + 2 < NT) asm volatile("s_waitcnt vmcnt(2)" ::: "memory");
      else            asm volatile("s_waitcnt vmcnt(0)" ::: "memory");
    }
    __builtin_amdgcn_s_barrier();
  }

  // ---------------- epilogue ----------------
#pragma unroll
  for (int m = 0; m < MR; ++m) {
#pragma unroll
    for (int n = 0; n < 4; ++n) {
      const int col = bcol + wn * 64 + n * 16 + lr;
      float bv, sc;
      if (MODE == 2) {
        const bool isV = (bcol >= 1024);
        bv = isV ? bias2[col - 1024] : bias[col];
        sc = isV ? 1.0f : LOG2E;
      } else {
        bv = bias[col];
        sc = scale;
      }
#pragma unroll
      for (int r = 0; r < 4; ++r) {
        const int row = brow + wm * (BM / 2) + m * 16 + rgrp + r;
        float v = acc[m][n][r] + bv;
        if (MODE == 1) {
          float res = (float)Resb[(size_t)row * N + col];
          Cb[(size_t)row * N + col] = (bf16)(res + (v > 0.f ? v : 0.f));
        } else {
          Cb[(size_t)row * N + col] = (bf16)(v * sc);
        }
      }
    }
  }
}

// ---------------- fused attention: 8 waves x 32 q, 32x32 MFMA, in-register P ----------
// grid (SQ/256, B*H), 512 threads. 2 blocks/CU -> 4 waves/SIMD (vs 2 before).
// qb pre-scaled 1/32, k pre-scaled log2e => P = exp2(S), no max subtraction.
__global__ __launch_bounds__(512, 4) void attn_kernel(
    const bf16* __restrict__ qb, const bf16* __restrict__ kvb,
    const bf16* __restrict__ vT, bf16* __restrict__ attnout) {
  const int bh = blockIdx.y;
  const int b = bh >> 4, h = bh & 15;
  const int tid = threadIdx.x, w = tid >> 6, lane = tid & 63;
  const int l31 = lane & 31;
  const int l1 = lane >> 5;
  const int q0w = blockIdx.x * 256 + w * 32;

  __shared__ __align__(16) bf16 Kl[2][64 * 64];
  __shared__ __align__(16) bf16 Vl[2][64 * 64];

  // staging: 512 threads cover 64 rows x 8 granules, one load per buffer each
  const int srow = tid >> 3;
  const int sgran = tid & 7;
  const int gsw = sgran ^ (srow & 7);   // pre-swizzled source granule
  const int ldst = srow * 64 + sgran * 8;
  const int rg = l31 & 7;               // read-side swizzle key

  const bf16* kbase = kvb + (size_t)(b * NSK) * 2048 + h * NDH;
  const bf16* vbase = vT + (size_t)(bh * NDH) * NSK;

  // Q fragments (B-operand): lane holds Q[q=l31][d = kd*16 + l1*8 + 0..7]
  bf16x8 qf[4];
#pragma unroll
  for (int kd = 0; kd < 4; ++kd)
    qf[kd] = *(const bf16x8*)&qb[(size_t)(b * NSQ + q0w + l31) * ND +
                                 h * NDH + kd * 16 + l1 * 8];

  f32x16 oacc0 = {}, oacc1 = {}, lacc = {};
  bf16x8 ones;
#pragma unroll
  for (int i = 0; i < 8; ++i) ones[i] = (bf16)1.0f;

  auto stage = [&](int bi, int kt) {
    async_load16(kbase + (size_t)(kt + srow) * 2048 + gsw * 8, &Kl[bi][ldst]);
    async_load16(vbase + (size_t)srow * NSK + kt + gsw * 8, &Vl[bi][ldst]);
  };

  stage(0, 0);

  for (int t = 0; t < 16; ++t) {
    const int bi = t & 1;
    asm volatile("s_waitcnt vmcnt(0)" ::: "memory");
    __syncthreads();
    if (t < 15) stage(bi ^ 1, (t + 1) * 64);

    uint32 W[2][4][2];
    // ---- n = 0 then n = 1 sequentially (caps VGPR pressure) ----
#pragma unroll
    for (int n = 0; n < 2; ++n) {
      f32x16 s = {};
      __builtin_amdgcn_s_setprio(1);
#pragma unroll
      for (int kd = 0; kd < 4; ++kd) {
        bf16x8 kf = *(const bf16x8*)&Kl[bi][(n * 32 + l31) * 64 + (((kd * 2 + l1) ^ rg) * 8)];
        s = __builtin_amdgcn_mfma_f32_32x32x16_bf16(kf, qf[kd], s, 0, 0, 0);
      }
      __builtin_amdgcn_s_setprio(0);
#pragma unroll
      for (int r2 = 0; r2 < 4; ++r2)
#pragma unroll
        for (int p = 0; p < 2; ++p) {
          float elo = __builtin_amdgcn_exp2f(s[r2 * 4 + 2 * p]);
          float ehi = __builtin_amdgcn_exp2f(s[r2 * 4 + 2 * p + 1]);
          uint32 wd;
          asm("v_cvt_pk_bf16_f32 %0, %1, %2" : "=v"(wd) : "v"(elo), "v"(ehi));
          W[n][r2][p] = wd;
        }
    }
    // redistribute to PV A-frags + PV
    __builtin_amdgcn_s_setprio(1);
#pragma unroll
    for (int kc = 0; kc < 4; ++kc) {
      uint32 x0 = W[kc >> 1][(kc & 1) * 2][0], y0 = W[kc >> 1][(kc & 1) * 2 + 1][0];
      uint32 x1 = W[kc >> 1][(kc & 1) * 2][1], y1 = W[kc >> 1][(kc & 1) * 2 + 1][1];
      permswap(x0, y0);
      permswap(x1, y1);
      union { uint32 u[4]; bf16x8 v; } cvt;
      cvt.u[0] = x0; cvt.u[1] = x1; cvt.u[2] = y0; cvt.u[3] = y1;
      bf16x8 pa = cvt.v;
      bf16x8 vf0 = *(const bf16x8*)&Vl[bi][(l31) * 64 + (((kc * 2 + l1) ^ rg) * 8)];
      bf16x8 vf1 = *(const bf16x8*)&Vl[bi][(32 + l31) * 64 + (((kc * 2 + l1) ^ rg) * 8)];
      oacc0 = __builtin_amdgcn_mfma_f32_32x32x16_bf16(pa, vf0, oacc0, 0, 0, 0);
      oacc1 = __builtin_amdgcn_mfma_f32_32x32x16_bf16(pa, vf1, oacc1, 0, 0, 0);
      lacc = __builtin_amdgcn_mfma_f32_32x32x16_bf16(pa, ones, lacc, 0, 0, 0);
    }
    __builtin_amdgcn_s_setprio(0);
  }

  // epilogue: lacc has identical row layout as oacc -> per-reg normalize
  float inv[16];
#pragma unroll
  for (int r = 0; r < 16; ++r) inv[r] = 1.0f / lacc[r];
#pragma unroll
  for (int r = 0; r < 16; ++r) {
    const int row = q0w + (r & 3) + 8 * (r >> 2) + 4 * l1;
    attnout[(size_t)(b * NSQ + row) * ND + h * NDH + l31] = (bf16)(oacc0[r] * inv[r]);
    attnout[(size_t)(b * NSQ + row) * ND + h * NDH + 32 + l31] = (bf16)(oacc1[r] * inv[r]);
  }
}

// ---------------- LayerNorm over bf16 input ----------------
template <bool RES, bool OUTF>
__global__ __launch_bounds__(256) void ln_kernel(
    const bf16* __restrict__ x, const bf16* __restrict__ rq, float rscale,
    const float* __restrict__ g, const float* __restrict__ be,
    bf16* __restrict__ yb, float* __restrict__ yf) {
  __shared__ float sm[4];
  const int row = blockIdx.x, tid = threadIdx.x;
  const size_t base = (size_t)row * ND + tid * 4;
  union { uint2 u; bf16 h[4]; } xv;
  xv.u = *(const uint2*)(x + base);
  float v0 = (float)xv.h[0], v1 = (float)xv.h[1], v2 = (float)xv.h[2], v3 = (float)xv.h[3];
  if (RES) {
    union { uint2 u; bf16 h[4]; } q;
    q.u = *(const uint2*)(rq + base);
    v0 += rscale * (float)q.h[0]; v1 += rscale * (float)q.h[1];
    v2 += rscale * (float)q.h[2]; v3 += rscale * (float)q.h[3];
  }
  float s = v0 + v1 + v2 + v3;
#pragma unroll
  for (int off = 32; off > 0; off >>= 1) s += __shfl_down(s, off, 64);
  if ((tid & 63) == 0) sm[tid >> 6] = s;
  __syncthreads();
  const float mean = (sm[0] + sm[1] + sm[2] + sm[3]) * (1.0f / ND);
  __syncthreads();
  const float d0 = v0 - mean, d1 = v1 - mean, d2 = v2 - mean, d3 = v3 - mean;
  float sq = d0 * d0 + d1 * d1 + d2 * d2 + d3 * d3;
#pragma unroll
  for (int off = 32; off > 0; off >>= 1) sq += __shfl_down(sq, off, 64);
  if ((tid & 63) == 0) sm[tid >> 6] = sq;
  __syncthreads();
  const float var = (sm[0] + sm[1] + sm[2] + sm[3]) * (1.0f / ND);
  const float rs = rsqrtf(var + 1e-5f);
  float4 gv = *(const float4*)(g + tid * 4);
  float4 bv = *(const float4*)(be + tid * 4);
  const float y0 = d0 * rs * gv.x + bv.x;
  const float y1 = d1 * rs * gv.y + bv.y;
  const float y2 = d2 * rs * gv.z + bv.z;
  const float y3 = d3 * rs * gv.w + bv.w;
  if (OUTF) {
    *(float4*)(yf + base) = make_float4(y0, y1, y2, y3);
  } else {
    union { uint2 u; bf16 h[4]; } o;
    o.h[0] = (bf16)y0; o.h[1] = (bf16)y1; o.h[2] = (bf16)y2; o.h[3] = (bf16)y3;
    *(uint2*)(yb + base) = o.u;
  }
}

extern "C" void kernel_launch(void* const* d_in, const int* in_sizes, int n_in,
                              void* d_out, int out_size, void* d_ws, size_t ws_size,
                              hipStream_t stream) {
  const float* Q  = (const float*)d_in[0];
  const float* K  = (const float*)d_in[1];
  const float* Wq = (const float*)d_in[2];
  const float* bq = (const float*)d_in[3];
  const float* Wk = (const float*)d_in[4];
  const float* bk = (const float*)d_in[5];
  const float* Wv = (const float*)d_in[6];
  const float* bv = (const float*)d_in[7];
  const float* Wo = (const float*)d_in[8];
  const float* bo = (const float*)d_in[9];
  const float* g0 = (const float*)d_in[10];
  const float* b0 = (const float*)d_in[11];
  const float* g1 = (const float*)d_in[12];
  const float* b1 = (const float*)d_in[13];
  float* out = (float*)d_out;

  char* ws = (char*)d_ws;
  const size_t MB = 1024 * 1024;
  bf16* Qb    = (bf16*)(ws + 0);          // 16MB
  bf16* Kb    = (bf16*)(ws + 16 * MB);    // 16MB
  bf16* Wqt   = (bf16*)(ws + 32 * MB);    // 2MB
  bf16* Wkvt  = (bf16*)(ws + 34 * MB);    // 4MB ([2048][1024])
  bf16* Wot   = (bf16*)(ws + 38 * MB);    // 2MB
  bf16* qb    = (bf16*)(ws + 40 * MB);    // 16MB
  bf16* kvb   = (bf16*)(ws + 56 * MB);    // 32MB ([8192][2048]: k | v)
  bf16* vT    = (bf16*)(ws + 88 * MB);    // 16MB
  bf16* attnb = (bf16*)(ws + 104 * MB);   // 16MB
  bf16* h0b   = (bf16*)(ws + 56 * MB);    // reuse kvb (dead after attn)
  bf16* out1b = (bf16*)(ws + 0);          // reuse Qb (dead after q GEMM)

  // 1. inputs -> bf16 (fused)
  cvt2_f32_bf16<<<dim3(8192, 2), 256, 0, stream>>>(Q, K, Qb, Kb);
  // 2. weights: transpose + convert (fused x4; Wk,Wv concatenated)
  transpose_cvt4<<<dim3(16, 16, 4), 256, 0, stream>>>(
      Wq, Wk, Wv, Wo, Wqt, Wkvt, Wkvt + 1024 * 1024, Wot);
  // 3. projections (q *= 1/32 exact; k *= log2e; v *= 1)
  gemm8p<256, 2, 8><<<256, 512, 0, stream>>>(Kb, Wkvt, bk, bv, kvb, nullptr, 1.0f, 2048);
  gemm8p<128, 0, 4><<<256, 512, 0, stream>>>(Qb, Wqt, bq, nullptr, qb, nullptr, 0.03125f, 1024);
  // 4. v -> vT per head
  transpose_v<<<dim3(16, 128), 256, 0, stream>>>(kvb, vT);
  // 5. attention (normalized bf16 out)
  attn_kernel<<<dim3(4, 128), 512, 0, stream>>>(qb, kvb, vT, attnb);
  // 6. h0 = LN(32*qb + attn)
  ln_kernel<true, false><<<8192, 256, 0, stream>>>(attnb, qb, 32.0f, g0, b0, h0b, nullptr);
  // 7. out1 = h0 + relu(h0 @ Wo + bo)
  gemm8p<128, 1, 4><<<256, 512, 0, stream>>>(h0b, Wot, bo, nullptr, out1b, h0b, 1.0f, 1024);
  // 8. out = LN(out1)
  ln_kernel<false, true><<<8192, 256, 0, stream>>>(out1b, nullptr, 0.f, g1, b1, nullptr, out);
}

// Round 9
// 180.059 us; speedup vs baseline: 1.7814x; 1.0113x over previous
//
#include <hip/hip_runtime.h>
#include <hip/hip_bf16.h>
#include <stdint.h>

// Problem dims
#define NB 8
#define NSQ 1024
#define NSK 1024
#define ND 1024
#define NH 16
#define NDH 64
#define NM (NB * NSQ)   // 8192 rows
#define LOG2E 1.4426950408889634f

typedef __bf16 bf16;
typedef __bf16 bf16x8 __attribute__((ext_vector_type(8)));
typedef float f32x4 __attribute__((ext_vector_type(4)));
typedef float f32x16 __attribute__((ext_vector_type(16)));
typedef unsigned int uint32;

// ---------------- async global->LDS (16B per lane) ----------------
__device__ __forceinline__ void async_load16(const void* g, void* l) {
  __builtin_amdgcn_global_load_lds(
      (__attribute__((address_space(1))) void*)g,
      (__attribute__((address_space(3))) void*)l, 16, 0, 0);
}

// half-swap: x' = {x.lo, y.lo}, y' = {x.hi, y.hi}
__device__ __forceinline__ void permswap(uint32& x, uint32& y) {
#if __has_builtin(__builtin_amdgcn_permlane32_swap)
  auto r = __builtin_amdgcn_permlane32_swap(x, y, false, false);
  x = r[0]; y = r[1];
#else
  asm volatile("v_permlane32_swap_b32 %0, %1" : "+v"(x), "+v"(y));
#endif
}

// ---------------- f32 -> bf16 converter (Q and K fused, grid.y selects) ----------------
__global__ __launch_bounds__(256) void cvt2_f32_bf16(const float* __restrict__ A,
                                                     const float* __restrict__ B,
                                                     bf16* __restrict__ Oa,
                                                     bf16* __restrict__ Ob) {
  const float* in = blockIdx.y ? B : A;
  bf16* out = blockIdx.y ? Ob : Oa;
  int i = blockIdx.x * 256 + threadIdx.x;
  float4 v = *(const float4*)(in + (size_t)i * 4);
  union { uint64_t u; bf16 h[4]; } o;
  o.h[0] = (bf16)v.x; o.h[1] = (bf16)v.y; o.h[2] = (bf16)v.z; o.h[3] = (bf16)v.w;
  *(uint64_t*)(out + (size_t)i * 4) = o.u;
}

// ---------------- 4x W [K,N] f32 -> Wt [N,K] bf16 (fused, grid.z selects) ----------------
__global__ __launch_bounds__(256) void transpose_cvt4(
    const float* __restrict__ W0, const float* __restrict__ W1,
    const float* __restrict__ W2, const float* __restrict__ W3,
    bf16* __restrict__ O0, bf16* __restrict__ O1,
    bf16* __restrict__ O2, bf16* __restrict__ O3) {
  const float* W; bf16* Wt;
  switch (blockIdx.z) {
    case 0: W = W0; Wt = O0; break;
    case 1: W = W1; Wt = O1; break;
    case 2: W = W2; Wt = O2; break;
    default: W = W3; Wt = O3; break;
  }
  __shared__ float t[64][65];
  const int bc = blockIdx.x * 64;
  const int br = blockIdx.y * 64;
  const int tid = threadIdx.x;
  for (int c = tid; c < 1024; c += 256) {
    int r = c >> 4, off = (c & 15) * 4;
    float4 v = *(const float4*)&W[(size_t)(br + r) * 1024 + bc + off];
    t[r][off] = v.x; t[r][off + 1] = v.y; t[r][off + 2] = v.z; t[r][off + 3] = v.w;
  }
  __syncthreads();
  for (int c = tid; c < 512; c += 256) {
    int cc = c >> 3, rr = (c & 7) * 8;
    union { uint4 u; bf16 h[8]; } o;
#pragma unroll
    for (int i = 0; i < 8; ++i) o.h[i] = (bf16)t[rr + i][cc];
    *(uint4*)&Wt[(size_t)(bc + cc) * 1024 + br + rr] = o.u;
  }
}

// ---------------- v (from kvb, stride 2048, offset 1024) -> vT [B,H,DH,SK] ----------------
__global__ __launch_bounds__(256) void transpose_v(const bf16* __restrict__ vsrc,
                                                   bf16* __restrict__ vT) {
  const int st = blockIdx.x * 64;
  const int bh = blockIdx.y;
  const int b = bh >> 4, h = bh & 15;
  __shared__ __align__(16) bf16 t[64][72];
  const int tid = threadIdx.x;
  for (int c = tid; c < 512; c += 256) {
    int s = c >> 3, off = (c & 7) * 8;
    *(uint4*)&t[s][off] =
        *(const uint4*)&vsrc[(size_t)(b * NSK + st + s) * 2048 + 1024 + h * NDH + off];
  }
  __syncthreads();
  for (int c = tid; c < 512; c += 256) {
    int d = c >> 3, s0 = (c & 7) * 8;
    union { uint4 u; bf16 h[8]; } o;
#pragma unroll
    for (int i = 0; i < 8; ++i) o.h[i] = t[s0 + i][d];
    *(uint4*)&vT[((size_t)(bh * NDH + d)) * NSK + st + s0] = o.u;
  }
}

// ---------------- gemm3b: C[M,N] = f(A[M,1024] @ Bt[N,1024]^T) ----------------
// BM x 128 block, 4 waves (2x2), BK=32, TRIPLE-buffered LDS, one barrier + counted
// vmcnt per K-tile, 2-tile-deep prefetch, granule-XOR LDS swizzle, XCD swizzle.
// Grid MUST be (M/BM)*(N/128) blocks (512 for all three GEMMs here -> 2 blocks/CU).
// MODE 0: Cb = bf16((acc+bias)*scale)
// MODE 1: Cb = bf16(Res + relu(acc+bias))
// MODE 2: fused KV (N=2048): tile col<1024 -> (acc+bk)*LOG2E ; else (acc+bv)
template <int BM, int MODE, int NXC>
__global__ __launch_bounds__(256, 2) void gemm3b(
    const bf16* __restrict__ A, const bf16* __restrict__ Bt,
    const float* __restrict__ bias, const float* __restrict__ bias2,
    bf16* __restrict__ Cb, const bf16* __restrict__ Resb, float scale, int N) {
  constexpr int NT = 32;                 // K = 1024 = 32 x 32
  constexpr int AR = BM / 64;            // A stage rounds (4 or 2)
  constexpr int MR = BM / 32;            // per-wave m-frags (8 or 4)
  __shared__ __align__(16) bf16 Asl[3][BM * 32];
  __shared__ __align__(16) bf16 Bsl[3][128 * 32];

  const int tid = threadIdx.x;
  const int flat = blockIdx.x;
  const int xi = (flat & 7) * 64 + (flat >> 3);   // 512 blocks -> bijective
  const int bcol = (xi & (NXC - 1)) * 128;
  const int brow = (xi / NXC) * BM;

  const int w = tid >> 6, lane = tid & 63;
  const int wm = w >> 1, wn = w & 1;              // 2 x 2 waves
  const int lr = lane & 15, l4 = lane >> 4;
  const int rgrp = l4 * 4;
  const int gph = (l4 ^ ((lr >> 1) & 3)) * 8;     // read-side swizzled granule

  // staging: round covers 64 rows; thread -> row tid>>2, dest granule tid&3,
  // source granule pre-swizzled: LDS(row,g) = global(row, g ^ ((row>>1)&3)).
  const int srow = tid >> 2;
  const int gsrc = (tid & 3) ^ ((tid >> 3) & 3);
  const bf16* Ag = A + (size_t)(brow + srow) * 1024 + gsrc * 8;
  const bf16* Bg = Bt + (size_t)(bcol + srow) * 1024 + gsrc * 8;
  const int ldo = srow * 32 + (tid & 3) * 8;

  auto stage = [&](int d, int kt) {   // AR + 2 loads per thread
#pragma unroll
    for (int r = 0; r < AR; ++r)
      async_load16(Ag + (size_t)r * (64 * 1024) + kt * 32, &Asl[d][r * 2048 + ldo]);
#pragma unroll
    for (int r = 0; r < 2; ++r)
      async_load16(Bg + (size_t)r * (64 * 1024) + kt * 32, &Bsl[d][r * 2048 + ldo]);
  };
  auto wait_tile = [&]() {   // wait until only the newest tile's loads remain
    if constexpr (BM == 256) asm volatile("s_waitcnt vmcnt(6)" ::: "memory");
    else                     asm volatile("s_waitcnt vmcnt(4)" ::: "memory");
  };

  f32x4 acc[MR][4] = {};

  stage(0, 0);
  stage(1, 1);
  wait_tile();                         // tile 0 landed
  __builtin_amdgcn_s_barrier();

  int cur = 0, st2 = 2;
  for (int t = 0; t < NT; ++t) {
    // ds_read this tile's fragments
    bf16x8 af[MR], bfr[4];
#pragma unroll
    for (int i = 0; i < MR; ++i)
      af[i] = *(const bf16x8*)&Asl[cur][(wm * (BM / 2) + i * 16 + lr) * 32 + gph];
#pragma unroll
    for (int n = 0; n < 4; ++n)
      bfr[n] = *(const bf16x8*)&Bsl[cur][(wn * 64 + n * 16 + lr) * 32 + gph];
    // issue tile t+2's loads (its buffer was last read at t-1; barrier passed)
    if (t + 2 < NT) stage(st2, t + 2);
    asm volatile("s_waitcnt lgkmcnt(0)" ::: "memory");
    __builtin_amdgcn_sched_barrier(0);
    __builtin_amdgcn_s_setprio(1);
#pragma unroll
    for (int i = 0; i < MR; ++i)
#pragma unroll
      for (int n = 0; n < 4; ++n)
        acc[i][n] = __builtin_amdgcn_mfma_f32_16x16x32_bf16(af[i], bfr[n], acc[i][n], 0, 0, 0);
    __builtin_amdgcn_s_setprio(0);
    // tile t+1 must be fully landed before next iteration reads it
    if (t + 2 < NT)      wait_tile();
    else if (t + 1 < NT) asm volatile("s_waitcnt vmcnt(0)" ::: "memory");
    __builtin_amdgcn_s_barrier();
    cur = (cur == 2) ? 0 : cur + 1;
    st2 = (st2 == 2) ? 0 : st2 + 1;
  }

  // ---------------- epilogue ----------------
#pragma unroll
  for (int m = 0; m < MR; ++m) {
#pragma unroll
    for (int n = 0; n < 4; ++n) {
      const int col = bcol + wn * 64 + n * 16 + lr;
      float bv, sc;
      if (MODE == 2) {
        const bool isV = (bcol >= 1024);
        bv = isV ? bias2[col - 1024] : bias[col];
        sc = isV ? 1.0f : LOG2E;
      } else {
        bv = bias[col];
        sc = scale;
      }
#pragma unroll
      for (int r = 0; r < 4; ++r) {
        const int row = brow + wm * (BM / 2) + m * 16 + rgrp + r;
        float v = acc[m][n][r] + bv;
        if (MODE == 1) {
          float res = (float)Resb[(size_t)row * N + col];
          Cb[(size_t)row * N + col] = (bf16)(res + (v > 0.f ? v : 0.f));
        } else {
          Cb[(size_t)row * N + col] = (bf16)(v * sc);
        }
      }
    }
  }
}

// ---------------- fused attention: 8 waves x 32 q, 32x32 MFMA, in-register P ----------
__global__ __launch_bounds__(512, 4) void attn_kernel(
    const bf16* __restrict__ qb, const bf16* __restrict__ kvb,
    const bf16* __restrict__ vT, bf16* __restrict__ attnout) {
  const int bh = blockIdx.y;
  const int b = bh >> 4, h = bh & 15;
  const int tid = threadIdx.x, w = tid >> 6, lane = tid & 63;
  const int l31 = lane & 31;
  const int l1 = lane >> 5;
  const int q0w = blockIdx.x * 256 + w * 32;

  __shared__ __align__(16) bf16 Kl[2][64 * 64];
  __shared__ __align__(16) bf16 Vl[2][64 * 64];

  const int srow = tid >> 3;
  const int sgran = tid & 7;
  const int gsw = sgran ^ (srow & 7);
  const int ldst = srow * 64 + sgran * 8;
  const int rg = l31 & 7;

  const bf16* kbase = kvb + (size_t)(b * NSK) * 2048 + h * NDH;
  const bf16* vbase = vT + (size_t)(bh * NDH) * NSK;

  bf16x8 qf[4];
#pragma unroll
  for (int kd = 0; kd < 4; ++kd)
    qf[kd] = *(const bf16x8*)&qb[(size_t)(b * NSQ + q0w + l31) * ND +
                                 h * NDH + kd * 16 + l1 * 8];

  f32x16 oacc0 = {}, oacc1 = {}, lacc = {};
  bf16x8 ones;
#pragma unroll
  for (int i = 0; i < 8; ++i) ones[i] = (bf16)1.0f;

  auto stage = [&](int bi, int kt) {
    async_load16(kbase + (size_t)(kt + srow) * 2048 + gsw * 8, &Kl[bi][ldst]);
    async_load16(vbase + (size_t)srow * NSK + kt + gsw * 8, &Vl[bi][ldst]);
  };

  stage(0, 0);

  for (int t = 0; t < 16; ++t) {
    const int bi = t & 1;
    asm volatile("s_waitcnt vmcnt(0)" ::: "memory");
    __syncthreads();
    if (t < 15) stage(bi ^ 1, (t + 1) * 64);

    uint32 W[2][4][2];
#pragma unroll
    for (int n = 0; n < 2; ++n) {
      f32x16 s = {};
      __builtin_amdgcn_s_setprio(1);
#pragma unroll
      for (int kd = 0; kd < 4; ++kd) {
        bf16x8 kf = *(const bf16x8*)&Kl[bi][(n * 32 + l31) * 64 + (((kd * 2 + l1) ^ rg) * 8)];
        s = __builtin_amdgcn_mfma_f32_32x32x16_bf16(kf, qf[kd], s, 0, 0, 0);
      }
      __builtin_amdgcn_s_setprio(0);
#pragma unroll
      for (int r2 = 0; r2 < 4; ++r2)
#pragma unroll
        for (int p = 0; p < 2; ++p) {
          float elo = __builtin_amdgcn_exp2f(s[r2 * 4 + 2 * p]);
          float ehi = __builtin_amdgcn_exp2f(s[r2 * 4 + 2 * p + 1]);
          uint32 wd;
          asm("v_cvt_pk_bf16_f32 %0, %1, %2" : "=v"(wd) : "v"(elo), "v"(ehi));
          W[n][r2][p] = wd;
        }
    }
    __builtin_amdgcn_s_setprio(1);
#pragma unroll
    for (int kc = 0; kc < 4; ++kc) {
      uint32 x0 = W[kc >> 1][(kc & 1) * 2][0], y0 = W[kc >> 1][(kc & 1) * 2 + 1][0];
      uint32 x1 = W[kc >> 1][(kc & 1) * 2][1], y1 = W[kc >> 1][(kc & 1) * 2 + 1][1];
      permswap(x0, y0);
      permswap(x1, y1);
      union { uint32 u[4]; bf16x8 v; } cvt;
      cvt.u[0] = x0; cvt.u[1] = x1; cvt.u[2] = y0; cvt.u[3] = y1;
      bf16x8 pa = cvt.v;
      bf16x8 vf0 = *(const bf16x8*)&Vl[bi][(l31) * 64 + (((kc * 2 + l1) ^ rg) * 8)];
      bf16x8 vf1 = *(const bf16x8*)&Vl[bi][(32 + l31) * 64 + (((kc * 2 + l1) ^ rg) * 8)];
      oacc0 = __builtin_amdgcn_mfma_f32_32x32x16_bf16(pa, vf0, oacc0, 0, 0, 0);
      oacc1 = __builtin_amdgcn_mfma_f32_32x32x16_bf16(pa, vf1, oacc1, 0, 0, 0);
      lacc = __builtin_amdgcn_mfma_f32_32x32x16_bf16(pa, ones, lacc, 0, 0, 0);
    }
    __builtin_amdgcn_s_setprio(0);
  }

  float inv[16];
#pragma unroll
  for (int r = 0; r < 16; ++r) inv[r] = 1.0f / lacc[r];
#pragma unroll
  for (int r = 0; r < 16; ++r) {
    const int row = q0w + (r & 3) + 8 * (r >> 2) + 4 * l1;
    attnout[(size_t)(b * NSQ + row) * ND + h * NDH + l31] = (bf16)(oacc0[r] * inv[r]);
    attnout[(size_t)(b * NSQ + row) * ND + h * NDH + 32 + l31] = (bf16)(oacc1[r] * inv[r]);
  }
}

// ---------------- LayerNorm over bf16 input ----------------
template <bool RES, bool OUTF>
__global__ __launch_bounds__(256) void ln_kernel(
    const bf16* __restrict__ x, const bf16* __restrict__ rq, float rscale,
    const float* __restrict__ g, const float* __restrict__ be,
    bf16* __restrict__ yb, float* __restrict__ yf) {
  __shared__ float sm[4];
  const int row = blockIdx.x, tid = threadIdx.x;
  const size_t base = (size_t)row * ND + tid * 4;
  union { uint2 u; bf16 h[4]; } xv;
  xv.u = *(const uint2*)(x + base);
  float v0 = (float)xv.h[0], v1 = (float)xv.h[1], v2 = (float)xv.h[2], v3 = (float)xv.h[3];
  if (RES) {
    union { uint2 u; bf16 h[4]; } q;
    q.u = *(const uint2*)(rq + base);
    v0 += rscale * (float)q.h[0]; v1 += rscale * (float)q.h[1];
    v2 += rscale * (float)q.h[2]; v3 += rscale * (float)q.h[3];
  }
  float s = v0 + v1 + v2 + v3;
#pragma unroll
  for (int off = 32; off > 0; off >>= 1) s += __shfl_down(s, off, 64);
  if ((tid & 63) == 0) sm[tid >> 6] = s;
  __syncthreads();
  const float mean = (sm[0] + sm[1] + sm[2] + sm[3]) * (1.0f / ND);
  __syncthreads();
  const float d0 = v0 - mean, d1 = v1 - mean, d2 = v2 - mean, d3 = v3 - mean;
  float sq = d0 * d0 + d1 * d1 + d2 * d2 + d3 * d3;
#pragma unroll
  for (int off = 32; off > 0; off >>= 1) sq += __shfl_down(sq, off, 64);
  if ((tid & 63) == 0) sm[tid >> 6] = sq;
  __syncthreads();
  const float var = (sm[0] + sm[1] + sm[2] + sm[3]) * (1.0f / ND);
  const float rs = rsqrtf(var + 1e-5f);
  float4 gv = *(const float4*)(g + tid * 4);
  float4 bv = *(const float4*)(be + tid * 4);
  const float y0 = d0 * rs * gv.x + bv.x;
  const float y1 = d1 * rs * gv.y + bv.y;
  const float y2 = d2 * rs * gv.z + bv.z;
  const float y3 = d3 * rs * gv.w + bv.w;
  if (OUTF) {
    *(float4*)(yf + base) = make_float4(y0, y1, y2, y3);
  } else {
    union { uint2 u; bf16 h[4]; } o;
    o.h[0] = (bf16)y0; o.h[1] = (bf16)y1; o.h[2] = (bf16)y2; o.h[3] = (bf16)y3;
    *(uint2*)(yb + base) = o.u;
  }
}

extern "C" void kernel_launch(void* const* d_in, const int* in_sizes, int n_in,
                              void* d_out, int out_size, void* d_ws, size_t ws_size,
                              hipStream_t stream) {
  const float* Q  = (const float*)d_in[0];
  const float* K  = (const float*)d_in[1];
  const float* Wq = (const float*)d_in[2];
  const float* bq = (const float*)d_in[3];
  const float* Wk = (const float*)d_in[4];
  const float* bk = (const float*)d_in[5];
  const float* Wv = (const float*)d_in[6];
  const float* bv = (const float*)d_in[7];
  const float* Wo = (const float*)d_in[8];
  const float* bo = (const float*)d_in[9];
  const float* g0 = (const float*)d_in[10];
  const float* b0 = (const float*)d_in[11];
  const float* g1 = (const float*)d_in[12];
  const float* b1 = (const float*)d_in[13];
  float* out = (float*)d_out;

  char* ws = (char*)d_ws;
  const size_t MB = 1024 * 1024;
  bf16* Qb    = (bf16*)(ws + 0);          // 16MB
  bf16* Kb    = (bf16*)(ws + 16 * MB);    // 16MB
  bf16* Wqt   = (bf16*)(ws + 32 * MB);    // 2MB
  bf16* Wkvt  = (bf16*)(ws + 34 * MB);    // 4MB ([2048][1024])
  bf16* Wot   = (bf16*)(ws + 38 * MB);    // 2MB
  bf16* qb    = (bf16*)(ws + 40 * MB);    // 16MB
  bf16* kvb   = (bf16*)(ws + 56 * MB);    // 32MB ([8192][2048]: k | v)
  bf16* vT    = (bf16*)(ws + 88 * MB);    // 16MB
  bf16* attnb = (bf16*)(ws + 104 * MB);   // 16MB
  bf16* h0b   = (bf16*)(ws + 56 * MB);    // reuse kvb (dead after attn)
  bf16* out1b = (bf16*)(ws + 0);          // reuse Qb (dead after q GEMM)

  // 1. inputs -> bf16 (fused)
  cvt2_f32_bf16<<<dim3(8192, 2), 256, 0, stream>>>(Q, K, Qb, Kb);
  // 2. weights: transpose + convert (fused x4; Wk,Wv concatenated)
  transpose_cvt4<<<dim3(16, 16, 4), 256, 0, stream>>>(
      Wq, Wk, Wv, Wo, Wqt, Wkvt, Wkvt + 1024 * 1024, Wot);
  // 3. projections (q *= 1/32 exact; k *= log2e; v *= 1)
  //    grids: (M/BM)*(N/128) = 512 for all three (2 blocks/CU)
  gemm3b<256, 2, 16><<<512, 256, 0, stream>>>(Kb, Wkvt, bk, bv, kvb, nullptr, 1.0f, 2048);
  gemm3b<128, 0, 8><<<512, 256, 0, stream>>>(Qb, Wqt, bq, nullptr, qb, nullptr, 0.03125f, 1024);
  // 4. v -> vT per head
  transpose_v<<<dim3(16, 128), 256, 0, stream>>>(kvb, vT);
  // 5. attention (normalized bf16 out)
  attn_kernel<<<dim3(4, 128), 512, 0, stream>>>(qb, kvb, vT, attnb);
  // 6. h0 = LN(32*qb + attn)
  ln_kernel<true, false><<<8192, 256, 0, stream>>>(attnb, qb, 32.0f, g0, b0, h0b, nullptr);
  // 7. out1 = h0 + relu(h0 @ Wo + bo)
  gemm3b<128, 1, 8><<<512, 256, 0, stream>>>(h0b, Wot, bo, nullptr, out1b, h0b, 1.0f, 1024);
  // 8. out = LN(out1)
  ln_kernel<false, true><<<8192, 256, 0, stream>>>(out1b, nullptr, 0.f, g1, b1, nullptr, out);
}